// Round 7
// baseline (738.445 us; speedup 1.0000x reference)
//
#include <hip/hip_runtime.h>

#define B_      8
#define N_      2048
#define DIM_    1024
#define HEADS_  8
#define CBD_    64
#define CBS_    1024
#define CBIN_   512              // HEADS_*CBD_
#define M_      (B_*N_)          // 16384 rows
#define M2_     (M_*HEADS_)      // 131072 row-heads

#define MARGIN 0.02f             // >> deterministic bf16x3 score error bound (~2.4e-3)
#define XSTR   40                // LDS stride (elements) for 32-k bf16 planes; 80 B = 16-B aligned

typedef unsigned short ushort_t;
typedef __attribute__((ext_vector_type(8))) short short8;
typedef __attribute__((ext_vector_type(4))) float f32x4;

__device__ inline ushort_t f2bf(float f) {
    unsigned int u = __builtin_bit_cast(unsigned int, f);
    unsigned int r = u + 0x7FFFu + ((u >> 16) & 1u);
    return (ushort_t)(r >> 16);
}
__device__ inline float bf2f(ushort_t h) {
    unsigned int u = ((unsigned int)h) << 16;
    return __builtin_bit_cast(float, u);
}
__device__ inline f32x4 mfma_bf16(short8 a, short8 b, f32x4 c) {
    return __builtin_amdgcn_mfma_f32_16x16x32_bf16(a, b, c, 0, 0, 0);
}
__device__ inline void store4u(ushort_t* p, ushort_t a, ushort_t b, ushort_t c, ushort_t d) {
    uint2 u;
    u.x = (unsigned int)a | ((unsigned int)b << 16);
    u.y = (unsigned int)c | ((unsigned int)d << 16);
    *(uint2*)p = u;
}
// 3-way bf16 split: f = s1 + s2 + s3 + O(2^-24 |f|)
__device__ inline void split3(float f, ushort_t& s1, ushort_t& s2, ushort_t& s3) {
    s1 = f2bf(f);
    float r = f - bf2f(s1);
    s2 = f2bf(r);
    float r2 = r - bf2f(s2);
    s3 = f2bf(r2);
}
// async 16-B global -> LDS (dest is wave-uniform base; HW adds lane*16)
__device__ inline void async_cp16(void* lds, const void* g) {
    __builtin_amdgcn_global_load_lds(
        (const __attribute__((address_space(1))) unsigned int*)g,
        (__attribute__((address_space(3))) unsigned int*)lds, 16, 0, 0);
}

// ---------------- prep: esq[c] = sum_d embed[c][d]^2 (fp32) ----------------
__global__ __launch_bounds__(256) void esq_kernel(const float* __restrict__ embed,
                                                  float* __restrict__ esq) {
    int c = blockIdx.x * 256 + threadIdx.x;
    if (c < CBS_) {
        const float* e = embed + (size_t)c * CBD_;
        float s = 0.f;
#pragma unroll
        for (int d = 0; d < CBD_; ++d) s += e[d] * e[d];
        esq[c] = s;
    }
}

// ---------------- prep: split embed into bf16 hi/lo, XOR-SWIZZLED layout ----------------
// Within each 128-B code row, 16-B slot s lands at slot s ^ (code&7). This makes the
// argmax2 ds_read_b128 pattern bank-optimal while keeping global_load_lds dests linear
// (rule: swizzle source + read together, never the LDS dest).
__global__ __launch_bounds__(256) void split_embed(const float* __restrict__ embed,
                                                   ushort_t* __restrict__ hi,
                                                   ushort_t* __restrict__ lo) {
    int i = blockIdx.x * 256 + threadIdx.x;   // 65536 total
    int code = i >> 6, d = i & 63;
    int dst = code * 64 + ((((d >> 3) ^ (code & 7)) << 3) | (d & 7));
    float f = embed[i];
    ushort_t hh = f2bf(f);
    hi[dst] = hh;
    lo[dst] = f2bf(f - bf2f(hh));
}

// ---------------- prep: WbfT[n][k] = bf16(W_out[k][n]) ----------------
__global__ __launch_bounds__(256) void transposeW(const float* __restrict__ W,
                                                  ushort_t* __restrict__ WT) {
    __shared__ ushort_t t[64][65];
    const int tid = threadIdx.x;
    const int n0 = blockIdx.x * 64, k0 = blockIdx.y * 64;
#pragma unroll
    for (int s = 0; s < 16; ++s) {
        int i = s * 256 + tid;
        int r = i >> 6, c = i & 63;
        t[r][c] = f2bf(W[(size_t)(k0 + r) * DIM_ + n0 + c]);
    }
    __syncthreads();
#pragma unroll
    for (int s = 0; s < 16; ++s) {
        int i = s * 256 + tid;
        int r = i >> 6, c = i & 63;
        WT[(size_t)(n0 + r) * CBIN_ + k0 + c] = t[c][r];
    }
}

// ---------------- prep: 3-way split + transpose of W_in: WpT[n][k] ----------------
__global__ __launch_bounds__(256) void split_WinT(const float* __restrict__ W,
                                                  ushort_t* __restrict__ W1T,
                                                  ushort_t* __restrict__ W2T,
                                                  ushort_t* __restrict__ W3T) {
    __shared__ ushort_t t1[64][65];
    __shared__ ushort_t t2[64][65];
    __shared__ ushort_t t3[64][65];
    const int tid = threadIdx.x;
    const int n0 = blockIdx.x * 64, k0 = blockIdx.y * 64;
#pragma unroll
    for (int s = 0; s < 16; ++s) {
        int i = s * 256 + tid;
        int r = i >> 6, c = i & 63;                 // r = k in tile, c = n in tile
        float f = W[(size_t)(k0 + r) * CBIN_ + n0 + c];
        split3(f, t1[r][c], t2[r][c], t3[r][c]);
    }
    __syncthreads();
#pragma unroll
    for (int s = 0; s < 16; ++s) {
        int i = s * 256 + tid;
        int r = i >> 6, c = i & 63;                 // r = n in tile, c = k in tile
        size_t o = (size_t)(n0 + r) * DIM_ + k0 + c;
        W1T[o] = t1[c][r];
        W2T[o] = t2[c][r];
        W3T[o] = t3[c][r];
    }
}

// ---------------- GEMM1 via bf16x6 MFMA: h[M,512] = x @ W_in + b_in ----------------
// 128x128 tile, BK=32, 8 waves (512 threads) in a 2x4 grid: wave tile 64x32.
// XCD panel swizzle: 4 col-blocks of a row-panel on one XCD (bijective).
__global__ __launch_bounds__(512) void gemm_in_x6(const float* __restrict__ x,
                                                  const ushort_t* __restrict__ W1T,
                                                  const ushort_t* __restrict__ W2T,
                                                  const ushort_t* __restrict__ W3T,
                                                  const float* __restrict__ bias,
                                                  float* __restrict__ C) {
    __shared__ ushort_t A1[128 * XSTR];
    __shared__ ushort_t A2[128 * XSTR];
    __shared__ ushort_t A3[128 * XSTR];
    __shared__ ushort_t B1[128 * XSTR];
    __shared__ ushort_t B2[128 * XSTR];
    __shared__ ushort_t B3[128 * XSTR];   // 6 * 10240 B = 61440 B

    const int tid  = threadIdx.x;
    const int lane = tid & 63;
    const int w    = tid >> 6;            // 0..7
    const int quad = lane >> 4;
    const int col  = lane & 15;

    // XCD-aware panel swizzle (dispatch slot -> (panel, colblk)), bijective
    const int slot   = blockIdx.y * 4 + blockIdx.x;   // dispatch order, x fastest
    const int g      = slot & 7;
    const int t      = slot >> 3;
    const int m0     = (g + 8 * (t >> 2)) * 128;
    const int n0     = (t & 3) * 128;

    const int wm   = (w & 1) * 64;        // 2 row groups of 64
    const int wn   = (w >> 1) * 32;       // 4 col groups of 32

    f32x4 acc[4][2];
#pragma unroll
    for (int rt = 0; rt < 4; ++rt)
#pragma unroll
        for (int ct = 0; ct < 2; ++ct) acc[rt][ct] = (f32x4){0.f, 0.f, 0.f, 0.f};

    for (int k0 = 0; k0 < DIM_; k0 += 32) {
        __syncthreads();
        // stage A: 128 rows x 32 k fp32 -> 3 bf16 planes (2 float4 per thread)
#pragma unroll
        for (int s = 0; s < 2; ++s) {
            int f = s * 512 + tid;
            int row = f >> 3, qq = f & 7;
            float4 v = *(const float4*)(x + (size_t)(m0 + row) * DIM_ + k0 + qq * 4);
            float vv[4] = {v.x, v.y, v.z, v.w};
            ushort_t p1[4], p2[4], p3[4];
#pragma unroll
            for (int j = 0; j < 4; ++j) split3(vv[j], p1[j], p2[j], p3[j]);
            int base = row * XSTR + qq * 4;
            store4u(&A1[base], p1[0], p1[1], p1[2], p1[3]);
            store4u(&A2[base], p2[0], p2[1], p2[2], p2[3]);
            store4u(&A3[base], p3[0], p3[1], p3[2], p3[3]);
        }
        // stage B planes: 128 n-rows x 32 k bf16 each (1 uint4 per thread per plane)
        {
            int row = tid >> 2, g2 = tid & 3;
            size_t go = (size_t)(n0 + row) * DIM_ + k0 + g2 * 8;
            int lo = row * XSTR + g2 * 8;
            *(uint4*)&B1[lo] = *(const uint4*)(W1T + go);
            *(uint4*)&B2[lo] = *(const uint4*)(W2T + go);
            *(uint4*)&B3[lo] = *(const uint4*)(W3T + go);
        }
        __syncthreads();

        short8 a1[4], a2[4], a3[4], b1[2], b2[2], b3[2];
#pragma unroll
        for (int rt = 0; rt < 4; ++rt) {
            int o = (wm + rt * 16 + col) * XSTR + quad * 8;
            a1[rt] = *(const short8*)&A1[o];
            a2[rt] = *(const short8*)&A2[o];
            a3[rt] = *(const short8*)&A3[o];
        }
#pragma unroll
        for (int ct = 0; ct < 2; ++ct) {
            int o = (wn + ct * 16 + col) * XSTR + quad * 8;
            b1[ct] = *(const short8*)&B1[o];
            b2[ct] = *(const short8*)&B2[o];
            b3[ct] = *(const short8*)&B3[o];
        }
#define COMBO(AP, BP)                                                   \
        _Pragma("unroll")                                               \
        for (int ct = 0; ct < 2; ++ct)                                  \
            _Pragma("unroll")                                           \
            for (int rt = 0; rt < 4; ++rt)                              \
                acc[rt][ct] = mfma_bf16(AP[rt], BP[ct], acc[rt][ct]);
        COMBO(a1, b1); COMBO(a1, b2); COMBO(a2, b1);
        COMBO(a2, b2); COMBO(a1, b3); COMBO(a3, b1);
#undef COMBO
    }

#pragma unroll
    for (int ct = 0; ct < 2; ++ct) {
        int gc = n0 + wn + ct * 16 + col;
        float bb = bias[gc];
#pragma unroll
        for (int rt = 0; rt < 4; ++rt) {
#pragma unroll
            for (int reg = 0; reg < 4; ++reg) {
                int gr = m0 + wm + rt * 16 + quad * 4 + reg;
                C[(size_t)gr * CBIN_ + gc] = acc[rt][ct][reg] + bb;
            }
        }
    }
}

// ---------------- argmax: A in regs, B TRIPLE-buffered via counted vmcnt ----------------
// Round-2 inner loop verbatim (spill-protected: no new live VGPRs). Staging upgraded to
// T3/T4: depth-2 prefetch into 3 LDS buffers; per-chunk sync is s_waitcnt vmcnt(4) +
// raw s_barrier (+sched_barrier, rule 18) so chunk ch+2's 4 global_load_lds stay IN
// FLIGHT across the barrier -- no per-chunk vmcnt(0) drain (the __syncthreads stall).
// vmcnt counts oldest-first (m135); loop fully unrolls so all immediates are static.
// Buffer safety: STAGE(ch+2) overwrites the buffer last read in chunk ch-1; the end-of-
// (ch-1) barrier separates those readers from this writer.
__global__ __launch_bounds__(256, 4) void argmax2(const float* __restrict__ h,
                                                  const ushort_t* __restrict__ ehswz,
                                                  const ushort_t* __restrict__ elswz,
                                                  const float* __restrict__ esq,
                                                  const float* __restrict__ embed,
                                                  float* __restrict__ outIdxF,
                                                  int* __restrict__ outIdxI) {
    __shared__ ushort_t EB[3 * 2 * 4096];   // 3 bufs x (hi,lo) x 4096 elems = 48 KB
    __shared__ float    ESQ[CBS_];
    __shared__ int BIDX[128];
    __shared__ int FLAG[128];
    __shared__ int NFLAG;

    const int tid  = threadIdx.x;
    const int lane = tid & 63;
    const int w    = tid >> 6;
    const int quad = lane >> 4;
    const int col  = lane & 15;
    const int r0   = blockIdx.x * 128;

    if (tid == 0) NFLAG = 0;
    *(float4*)&ESQ[tid * 4] = *(const float4*)(esq + tid * 4);

    // A fragments: wave reads 16 contiguous rows x 256 B, split hi/lo in regs
    short8 AH[2][2], AL[2][2];
#pragma unroll
    for (int rt = 0; rt < 2; ++rt) {
        const float* hp = h + (size_t)(r0 + w * 32 + rt * 16 + col) * 64 + quad * 8;
#pragma unroll
        for (int ks = 0; ks < 2; ++ks) {
            float4 u0 = *(const float4*)(hp + ks * 32);
            float4 u1 = *(const float4*)(hp + ks * 32 + 4);
            float vv[8] = {u0.x, u0.y, u0.z, u0.w, u1.x, u1.y, u1.z, u1.w};
            short8 hh, ll;
#pragma unroll
            for (int j = 0; j < 8; ++j) {
                ushort_t hi = f2bf(vv[j]);
                hh[j] = (short)hi;
                ll[j] = (short)f2bf(vv[j] - bf2f(hi));
            }
            AH[rt][ks] = hh;
            AL[rt][ks] = ll;
        }
    }

    // stage chunk ch into buffer b: 4 async 16-B copies (hi/lo x two 4-KB slices)
#define STAGE(ch, b)                                                          \
    do {                                                                      \
        int eo = (ch) * 4096 + tid * 8;                                       \
        int dz = (b) * 8192 + w * 512;                                        \
        async_cp16(&EB[dz],        ehswz + eo);                               \
        async_cp16(&EB[dz + 2048], ehswz + eo + 2048);                        \
        async_cp16(&EB[dz + 4096],        elswz + eo);                        \
        async_cp16(&EB[dz + 4096 + 2048], elswz + eo + 2048);                 \
    } while (0)

    STAGE(0, 0);
    STAGE(1, 1);

    float v1[8], v2[8];
    int   i1[8];
#pragma unroll
    for (int s = 0; s < 8; ++s) { v1[s] = -3.4e38f; v2[s] = -3.4e38f; i1[s] = 0; }

    __syncthreads();   // full drain once: chunks 0,1 staged; ESQ + NFLAG visible

    int cur = 0;
#pragma unroll
    for (int ch = 0; ch < 16; ++ch) {
        if (ch < 14) STAGE(ch + 2, (cur == 0) ? 2 : cur - 1);   // (cur+2)%3
        const int bz = cur * 8192;
#pragma unroll
        for (int ct = 0; ct < 4; ++ct) {
            const int lc = ct * 16 + col;
            const int x7 = col & 7;
            const int o0 = lc * 64 + (((quad)     ^ x7) << 3);
            const int o1 = lc * 64 + (((quad + 4) ^ x7) << 3);
            short8 BH0 = *(const short8*)&EB[bz + o0];
            short8 BH1 = *(const short8*)&EB[bz + o1];
            short8 BL0 = *(const short8*)&EB[bz + 4096 + o0];
            short8 BL1 = *(const short8*)&EB[bz + 4096 + o1];
            const int code = ch * 64 + lc;
            float eq = ESQ[code];
#pragma unroll
            for (int rt = 0; rt < 2; ++rt) {
                f32x4 acc = {0.f, 0.f, 0.f, 0.f};
                acc = mfma_bf16(AH[rt][0], BH0, acc);
                acc = mfma_bf16(AH[rt][1], BH1, acc);
                acc = mfma_bf16(AH[rt][0], BL0, acc);
                acc = mfma_bf16(AH[rt][1], BL1, acc);
                acc = mfma_bf16(AL[rt][0], BH0, acc);
                acc = mfma_bf16(AL[rt][1], BH1, acc);
#pragma unroll
                for (int reg = 0; reg < 4; ++reg) {
                    const int st = rt * 4 + reg;
                    float sc = fmaf(2.f, acc[reg], -eq);
                    // runner-up: median(sc, v1, v2) == max(v2, min(sc, v1))
                    v2[st] = __builtin_amdgcn_fmed3f(sc, v1[st], v2[st]);
                    bool gt = sc > v1[st];
                    v1[st] = fmaxf(v1[st], sc);
                    i1[st] = gt ? code : i1[st];
                }
            }
        }
        if (ch < 15) {
            // next chunk's 4 loads must have landed; newest 4 (chunk ch+2) may fly on
            if (ch < 14) asm volatile("s_waitcnt vmcnt(4)" ::: "memory");
            else         asm volatile("s_waitcnt vmcnt(0)" ::: "memory");
            __builtin_amdgcn_s_barrier();
            __builtin_amdgcn_sched_barrier(0);
        }
        cur = (cur == 2) ? 0 : cur + 1;
    }
#undef STAGE

#pragma unroll
    for (int st = 0; st < 8; ++st) {
#pragma unroll
        for (int m = 1; m <= 8; m <<= 1) {
            float ov1 = __shfl_xor(v1[st], m);
            int   oi1 = __shfl_xor(i1[st], m);
            float ov2 = __shfl_xor(v2[st], m);
            float losr = fminf(v1[st], ov1);
            v2[st] = fmaxf(fmaxf(v2[st], ov2), losr);
            bool take = (ov1 > v1[st]) || (ov1 == v1[st] && oi1 < i1[st]);
            v1[st] = take ? ov1 : v1[st];
            i1[st] = take ? oi1 : i1[st];
        }
        if (col == 0) {
            int rt = st >> 2, reg = st & 3;
            int row_l = w * 32 + rt * 16 + quad * 4 + reg;
            BIDX[row_l] = i1[st];
            if (v1[st] - v2[st] < MARGIN) {
                int p = atomicAdd(&NFLAG, 1);
                FLAG[p] = row_l;
            }
        }
    }
    __syncthreads();

    int nf = NFLAG;
    for (int i = w; i < nf; i += 4) {
        int row_l = FLAG[i];
        const float* hr = h + (size_t)(r0 + row_l) * 64;
        float accf[16];
#pragma unroll
        for (int j = 0; j < 16; ++j) accf[j] = 0.f;
        for (int d4 = 0; d4 < 16; ++d4) {
            float4 hv = *(const float4*)(hr + d4 * 4);
#pragma unroll
            for (int j = 0; j < 16; ++j) {
                int c = lane + 64 * j;
                float4 ev = *(const float4*)(embed + (size_t)c * 64 + d4 * 4);
                accf[j] += hv.x * ev.x + hv.y * ev.y + hv.z * ev.z + hv.w * ev.w;
            }
        }
        float best = -3.4e38f; int bi = 0;
#pragma unroll
        for (int j = 0; j < 16; ++j) {
            int c = lane + 64 * j;
            float sc = 2.f * accf[j] - ESQ[c];
            if (sc > best) { best = sc; bi = c; }
        }
#pragma unroll
        for (int m = 1; m <= 32; m <<= 1) {
            float ob = __shfl_xor(best, m);
            int  obi = __shfl_xor(bi, m);
            if (ob > best || (ob == best && obi < bi)) { best = ob; bi = obi; }
        }
        if (lane == 0) BIDX[row_l] = bi;
    }
    __syncthreads();

    if (tid < 128) {
        int b = BIDX[tid];
        outIdxF[r0 + tid] = (float)b;
        outIdxI[r0 + tid] = b;
    }
}

// ---------------- GEMM3 (bf16 MFMA): out = gather(ehswz, idx) @ W_out + b_out ----------
// Gather un-swizzles with the same slot XOR (row stays 128 B contiguous).
__global__ __launch_bounds__(256) void gemm_out_bf16(const ushort_t* __restrict__ ehswz,
                                                     const int* __restrict__ idx,
                                                     const ushort_t* __restrict__ WbfT,
                                                     const float* __restrict__ bias,
                                                     float* __restrict__ C) {
    __shared__ ushort_t Qs[128 * 72];
    __shared__ ushort_t Ws[128 * 72];
    __shared__ int idxs[128 * HEADS_];

    const int tid  = threadIdx.x;
    const int lane = tid & 63;
    const int w    = tid >> 6;
    const int quad = lane >> 4;
    const int col  = lane & 15;
    const int m0   = blockIdx.y * 128;
    const int n0   = blockIdx.x * 128;
    const int wm   = (w & 1) * 64;
    const int wn   = (w >> 1) * 64;

#pragma unroll
    for (int s = 0; s < 4; ++s) {
        int f = s * 256 + tid;
        idxs[f] = idx[(size_t)m0 * HEADS_ + f];
    }

    f32x4 acc[4][4];
#pragma unroll
    for (int rt = 0; rt < 4; ++rt)
#pragma unroll
        for (int ct = 0; ct < 4; ++ct) acc[rt][ct] = (f32x4){0.f, 0.f, 0.f, 0.f};

    for (int k0 = 0; k0 < CBIN_; k0 += 64) {
        __syncthreads();
        int head = k0 >> 6;
#pragma unroll
        for (int s = 0; s < 4; ++s) {
            int f = s * 256 + tid;
            int row = f >> 3, g = f & 7;
            int e = idxs[row * HEADS_ + head];
            *(uint4*)&Qs[row * 72 + g * 8] =
                *(const uint4*)(ehswz + (size_t)e * 64 + ((g ^ (e & 7)) << 3));
            *(uint4*)&Ws[row * 72 + g * 8] =
                *(const uint4*)(WbfT + (size_t)(n0 + row) * CBIN_ + k0 + g * 8);
        }
        __syncthreads();
#pragma unroll
        for (int ks = 0; ks < 2; ++ks) {
            short8 a[4], b[4];
#pragma unroll
            for (int rt = 0; rt < 4; ++rt)
                a[rt] = *(const short8*)&Qs[(wm + rt * 16 + col) * 72 + ks * 32 + quad * 8];
#pragma unroll
            for (int ct = 0; ct < 4; ++ct)
                b[ct] = *(const short8*)&Ws[(wn + ct * 16 + col) * 72 + ks * 32 + quad * 8];
#pragma unroll
            for (int rt = 0; rt < 4; ++rt)
#pragma unroll
                for (int ct = 0; ct < 4; ++ct)
                    acc[rt][ct] = mfma_bf16(a[rt], b[ct], acc[rt][ct]);
        }
    }

#pragma unroll
    for (int ct = 0; ct < 4; ++ct) {
        int gc = n0 + wn + ct * 16 + col;
        float bb = bias[gc];
#pragma unroll
        for (int rt = 0; rt < 4; ++rt) {
#pragma unroll
            for (int reg = 0; reg < 4; ++reg) {
                int gr = m0 + wm + rt * 16 + quad * 4 + reg;
                C[(size_t)gr * DIM_ + gc] = acc[rt][ct][reg] + bb;
            }
        }
    }
}

extern "C" void kernel_launch(void* const* d_in, const int* in_sizes, int n_in,
                              void* d_out, int out_size, void* d_ws, size_t ws_size,
                              hipStream_t stream) {
    const float* x     = (const float*)d_in[0];
    const float* W_in  = (const float*)d_in[1];
    const float* b_in  = (const float*)d_in[2];
    const float* W_out = (const float*)d_in[3];
    const float* b_out = (const float*)d_in[4];
    const float* embed = (const float*)d_in[5];

    float* out     = (float*)d_out;
    float* outIdxF = out + (size_t)M_ * DIM_;

    // workspace layout (38.5 MB total)
    char* ws = (char*)d_ws;
    float*    h     = (float*)ws;                                   // 33,554,432 B
    int*      idxI  = (int*)(ws + 33554432);                        //    524,288 B
    float*    esq   = (float*)(ws + 34078720);                      //      4,096 B
    ushort_t* ehswz = (ushort_t*)(ws + 34082816);                   //    131,072 B (swizzled hi)
    ushort_t* elswz = (ushort_t*)(ws + 34213888);                   //    131,072 B (swizzled lo)
    ushort_t* WbfT  = (ushort_t*)(ws + 34344960);                   //  1,048,576 B
    ushort_t* W1T   = (ushort_t*)(ws + 35393536);                   //  1,048,576 B
    ushort_t* W2T   = (ushort_t*)(ws + 36442112);                   //  1,048,576 B
    ushort_t* W3T   = (ushort_t*)(ws + 37490688);                   //  1,048,576 B

    esq_kernel<<<dim3(CBS_ / 256), dim3(256), 0, stream>>>(embed, esq);
    split_embed<<<dim3(CBS_ * CBD_ / 256), dim3(256), 0, stream>>>(embed, ehswz, elswz);
    transposeW<<<dim3(DIM_ / 64, CBIN_ / 64), dim3(256), 0, stream>>>(W_out, WbfT);
    split_WinT<<<dim3(CBIN_ / 64, DIM_ / 64), dim3(256), 0, stream>>>(W_in, W1T, W2T, W3T);
    gemm_in_x6<<<dim3(CBIN_ / 128, M_ / 128), dim3(512), 0, stream>>>(x, W1T, W2T, W3T,
                                                                      b_in, h);
    argmax2<<<dim3(M2_ / 128), dim3(256), 0, stream>>>(h, ehswz, elswz, esq, embed,
                                                       outIdxF, idxI);
    gemm_out_bf16<<<dim3(DIM_ / 128, M_ / 128), dim3(256), 0, stream>>>(ehswz, idxI, WbfT,
                                                                        b_out, out);
}

// Round 8
// 370.431 us; speedup vs baseline: 1.9935x; 1.9935x over previous
//
#include <hip/hip_runtime.h>

#define B_      8
#define N_      2048
#define DIM_    1024
#define HEADS_  8
#define CBD_    64
#define CBS_    1024
#define CBIN_   512              // HEADS_*CBD_
#define M_      (B_*N_)          // 16384 rows
#define M2_     (M_*HEADS_)      // 131072 row-heads

#define MARGIN 0.02f             // >> deterministic bf16x3 score error bound (~2.4e-3)
#define XSTR   40                // LDS stride (elements) for 32-k bf16 planes; 80 B = 16-B aligned

typedef unsigned short ushort_t;
typedef __attribute__((ext_vector_type(8))) short short8;
typedef __attribute__((ext_vector_type(4))) float f32x4;

__device__ inline ushort_t f2bf(float f) {
    unsigned int u = __builtin_bit_cast(unsigned int, f);
    unsigned int r = u + 0x7FFFu + ((u >> 16) & 1u);
    return (ushort_t)(r >> 16);
}
__device__ inline float bf2f(ushort_t h) {
    unsigned int u = ((unsigned int)h) << 16;
    return __builtin_bit_cast(float, u);
}
__device__ inline f32x4 mfma_bf16(short8 a, short8 b, f32x4 c) {
    return __builtin_amdgcn_mfma_f32_16x16x32_bf16(a, b, c, 0, 0, 0);
}
__device__ inline void store4u(ushort_t* p, ushort_t a, ushort_t b, ushort_t c, ushort_t d) {
    uint2 u;
    u.x = (unsigned int)a | ((unsigned int)b << 16);
    u.y = (unsigned int)c | ((unsigned int)d << 16);
    *(uint2*)p = u;
}
// 3-way bf16 split: f = s1 + s2 + s3 + O(2^-24 |f|)
__device__ inline void split3(float f, ushort_t& s1, ushort_t& s2, ushort_t& s3) {
    s1 = f2bf(f);
    float r = f - bf2f(s1);
    s2 = f2bf(r);
    float r2 = r - bf2f(s2);
    s3 = f2bf(r2);
}
// async 16-B global -> LDS (dest is wave-uniform base; HW adds lane*16)
__device__ inline void async_cp16(void* lds, const void* g) {
    __builtin_amdgcn_global_load_lds(
        (const __attribute__((address_space(1))) unsigned int*)g,
        (__attribute__((address_space(3))) unsigned int*)lds, 16, 0, 0);
}

// ---------------- prep: esq[c] = sum_d embed[c][d]^2 (fp32) ----------------
__global__ __launch_bounds__(256) void esq_kernel(const float* __restrict__ embed,
                                                  float* __restrict__ esq) {
    int c = blockIdx.x * 256 + threadIdx.x;
    if (c < CBS_) {
        const float* e = embed + (size_t)c * CBD_;
        float s = 0.f;
#pragma unroll
        for (int d = 0; d < CBD_; ++d) s += e[d] * e[d];
        esq[c] = s;
    }
}

// ---------------- prep: split embed into bf16 hi/lo, XOR-SWIZZLED layout ----------------
// Within each 128-B code row, 16-B slot s lands at slot s ^ (code&7). argmax2 reads it
// with the matching XOR; gemm_out's gather un-XORs per-lane on the global source.
__global__ __launch_bounds__(256) void split_embed(const float* __restrict__ embed,
                                                   ushort_t* __restrict__ hi,
                                                   ushort_t* __restrict__ lo) {
    int i = blockIdx.x * 256 + threadIdx.x;   // 65536 total
    int code = i >> 6, d = i & 63;
    int dst = code * 64 + ((((d >> 3) ^ (code & 7)) << 3) | (d & 7));
    float f = embed[i];
    ushort_t hh = f2bf(f);
    hi[dst] = hh;
    lo[dst] = f2bf(f - bf2f(hh));
}

// ---------------- prep: WbfT[n][k] = bf16(W_out[k][n]) ----------------
__global__ __launch_bounds__(256) void transposeW(const float* __restrict__ W,
                                                  ushort_t* __restrict__ WT) {
    __shared__ ushort_t t[64][65];
    const int tid = threadIdx.x;
    const int n0 = blockIdx.x * 64, k0 = blockIdx.y * 64;
#pragma unroll
    for (int s = 0; s < 16; ++s) {
        int i = s * 256 + tid;
        int r = i >> 6, c = i & 63;
        t[r][c] = f2bf(W[(size_t)(k0 + r) * DIM_ + n0 + c]);
    }
    __syncthreads();
#pragma unroll
    for (int s = 0; s < 16; ++s) {
        int i = s * 256 + tid;
        int r = i >> 6, c = i & 63;
        WT[(size_t)(n0 + r) * CBIN_ + k0 + c] = t[c][r];
    }
}

// ---------------- prep: 3-way split + transpose of W_in: WpT[n][k] ----------------
__global__ __launch_bounds__(256) void split_WinT(const float* __restrict__ W,
                                                  ushort_t* __restrict__ W1T,
                                                  ushort_t* __restrict__ W2T,
                                                  ushort_t* __restrict__ W3T) {
    __shared__ ushort_t t1[64][65];
    __shared__ ushort_t t2[64][65];
    __shared__ ushort_t t3[64][65];
    const int tid = threadIdx.x;
    const int n0 = blockIdx.x * 64, k0 = blockIdx.y * 64;
#pragma unroll
    for (int s = 0; s < 16; ++s) {
        int i = s * 256 + tid;
        int r = i >> 6, c = i & 63;                 // r = k in tile, c = n in tile
        float f = W[(size_t)(k0 + r) * CBIN_ + n0 + c];
        split3(f, t1[r][c], t2[r][c], t3[r][c]);
    }
    __syncthreads();
#pragma unroll
    for (int s = 0; s < 16; ++s) {
        int i = s * 256 + tid;
        int r = i >> 6, c = i & 63;                 // r = n in tile, c = k in tile
        size_t o = (size_t)(n0 + r) * DIM_ + k0 + c;
        W1T[o] = t1[c][r];
        W2T[o] = t2[c][r];
        W3T[o] = t3[c][r];
    }
}

// ---------------- GEMM1 via bf16x6 MFMA: h[M,512] = x @ W_in + b_in ----------------
// Round-5 version (proven): 128x128 tile, BK=32, 8 waves, wave tile 64x32, XCD swizzle.
__global__ __launch_bounds__(512) void gemm_in_x6(const float* __restrict__ x,
                                                  const ushort_t* __restrict__ W1T,
                                                  const ushort_t* __restrict__ W2T,
                                                  const ushort_t* __restrict__ W3T,
                                                  const float* __restrict__ bias,
                                                  float* __restrict__ C) {
    __shared__ ushort_t A1[128 * XSTR];
    __shared__ ushort_t A2[128 * XSTR];
    __shared__ ushort_t A3[128 * XSTR];
    __shared__ ushort_t B1[128 * XSTR];
    __shared__ ushort_t B2[128 * XSTR];
    __shared__ ushort_t B3[128 * XSTR];   // 6 * 10240 B = 61440 B

    const int tid  = threadIdx.x;
    const int lane = tid & 63;
    const int w    = tid >> 6;            // 0..7
    const int quad = lane >> 4;
    const int col  = lane & 15;

    const int slot   = blockIdx.y * 4 + blockIdx.x;   // dispatch order, x fastest
    const int g      = slot & 7;
    const int t      = slot >> 3;
    const int m0     = (g + 8 * (t >> 2)) * 128;
    const int n0     = (t & 3) * 128;

    const int wm   = (w & 1) * 64;        // 2 row groups of 64
    const int wn   = (w >> 1) * 32;       // 4 col groups of 32

    f32x4 acc[4][2];
#pragma unroll
    for (int rt = 0; rt < 4; ++rt)
#pragma unroll
        for (int ct = 0; ct < 2; ++ct) acc[rt][ct] = (f32x4){0.f, 0.f, 0.f, 0.f};

    for (int k0 = 0; k0 < DIM_; k0 += 32) {
        __syncthreads();
#pragma unroll
        for (int s = 0; s < 2; ++s) {
            int f = s * 512 + tid;
            int row = f >> 3, qq = f & 7;
            float4 v = *(const float4*)(x + (size_t)(m0 + row) * DIM_ + k0 + qq * 4);
            float vv[4] = {v.x, v.y, v.z, v.w};
            ushort_t p1[4], p2[4], p3[4];
#pragma unroll
            for (int j = 0; j < 4; ++j) split3(vv[j], p1[j], p2[j], p3[j]);
            int base = row * XSTR + qq * 4;
            store4u(&A1[base], p1[0], p1[1], p1[2], p1[3]);
            store4u(&A2[base], p2[0], p2[1], p2[2], p2[3]);
            store4u(&A3[base], p3[0], p3[1], p3[2], p3[3]);
        }
        {
            int row = tid >> 2, g2 = tid & 3;
            size_t go = (size_t)(n0 + row) * DIM_ + k0 + g2 * 8;
            int lo = row * XSTR + g2 * 8;
            *(uint4*)&B1[lo] = *(const uint4*)(W1T + go);
            *(uint4*)&B2[lo] = *(const uint4*)(W2T + go);
            *(uint4*)&B3[lo] = *(const uint4*)(W3T + go);
        }
        __syncthreads();

        short8 a1[4], a2[4], a3[4], b1[2], b2[2], b3[2];
#pragma unroll
        for (int rt = 0; rt < 4; ++rt) {
            int o = (wm + rt * 16 + col) * XSTR + quad * 8;
            a1[rt] = *(const short8*)&A1[o];
            a2[rt] = *(const short8*)&A2[o];
            a3[rt] = *(const short8*)&A3[o];
        }
#pragma unroll
        for (int ct = 0; ct < 2; ++ct) {
            int o = (wn + ct * 16 + col) * XSTR + quad * 8;
            b1[ct] = *(const short8*)&B1[o];
            b2[ct] = *(const short8*)&B2[o];
            b3[ct] = *(const short8*)&B3[o];
        }
#define COMBO(AP, BP)                                                   \
        _Pragma("unroll")                                               \
        for (int ct = 0; ct < 2; ++ct)                                  \
            _Pragma("unroll")                                           \
            for (int rt = 0; rt < 4; ++rt)                              \
                acc[rt][ct] = mfma_bf16(AP[rt], BP[ct], acc[rt][ct]);
        COMBO(a1, b1); COMBO(a1, b2); COMBO(a2, b1);
        COMBO(a2, b2); COMBO(a1, b3); COMBO(a3, b1);
#undef COMBO
    }

#pragma unroll
    for (int ct = 0; ct < 2; ++ct) {
        int gc = n0 + wn + ct * 16 + col;
        float bb = bias[gc];
#pragma unroll
        for (int rt = 0; rt < 4; ++rt) {
#pragma unroll
            for (int reg = 0; reg < 4; ++reg) {
                int gr = m0 + wm + rt * 16 + quad * 4 + reg;
                C[(size_t)gr * CBIN_ + gc] = acc[rt][ct][reg] + bb;
            }
        }
    }
}

// ---------------- argmax: round-5 body + counted-vmcnt triple buffer (ROLLED loop) -----
// Round-7's failure was the `#pragma unroll` on the ch loop (16x code explosion -> 256
// VGPR, ~770 MB scratch). The counted-vmcnt immediates never needed unrolling. This
// version keeps the round-2/5 rolled-loop register profile (64 VGPR) and only changes:
// (a) 3 buffers, depth-2 prefetch; (b) per-chunk sync = s_waitcnt vmcnt(4) + raw
// s_barrier + sched_barrier, so the newest 4 global_load_lds cross the barrier in
// flight; (c) BIDX/FLAG/NFLAG alias EB (dead after main loop) so LDS = 53.2 KB ->
// 3 blocks/CU. vmcnt ledger: at end-of-ch, outstanding = STAGE(ch+1)[oldest 4] +
// STAGE(ch+2)[newest 4]; vmcnt(4) retires the oldest 4. Buffer (cur+2)%3 was last read
// in chunk ch-1, whose barrier precedes this overwrite. DO NOT add live VGPRs here.
__global__ __launch_bounds__(256, 4) void argmax2(const float* __restrict__ h,
                                                  const ushort_t* __restrict__ ehswz,
                                                  const ushort_t* __restrict__ elswz,
                                                  const float* __restrict__ esq,
                                                  const float* __restrict__ embed,
                                                  float* __restrict__ outIdxF,
                                                  int* __restrict__ outIdxI) {
    __shared__ ushort_t EB[3 * 8192];     // 3 bufs x (hi 4096 | lo 4096) = 49152 B
    __shared__ float    ESQ[CBS_];        // 4096 B  (total 53248 B -> 3 blocks/CU)

    const int tid  = threadIdx.x;
    const int lane = tid & 63;
    const int w    = tid >> 6;
    const int quad = lane >> 4;
    const int col  = lane & 15;
    const int r0   = blockIdx.x * 128;

    *(float4*)&ESQ[tid * 4] = *(const float4*)(esq + tid * 4);

    // A fragments: wave reads 16 contiguous rows x 256 B, split hi/lo in regs
    short8 AH[2][2], AL[2][2];
#pragma unroll
    for (int rt = 0; rt < 2; ++rt) {
        const float* hp = h + (size_t)(r0 + w * 32 + rt * 16 + col) * 64 + quad * 8;
#pragma unroll
        for (int ks = 0; ks < 2; ++ks) {
            float4 u0 = *(const float4*)(hp + ks * 32);
            float4 u1 = *(const float4*)(hp + ks * 32 + 4);
            float vv[8] = {u0.x, u0.y, u0.z, u0.w, u1.x, u1.y, u1.z, u1.w};
            short8 hh, ll;
#pragma unroll
            for (int j = 0; j < 8; ++j) {
                ushort_t hi = f2bf(vv[j]);
                hh[j] = (short)hi;
                ll[j] = (short)f2bf(vv[j] - bf2f(hi));
            }
            AH[rt][ks] = hh;
            AL[rt][ks] = ll;
        }
    }

    // stage chunk ch into buffer b: 4 async 16-B copies (hi/lo x two 4-KB slices)
#define STAGE(ch, b)                                                          \
    do {                                                                      \
        int eo = (ch) * 4096 + tid * 8;                                       \
        int dz = (b) * 8192 + w * 512;                                        \
        async_cp16(&EB[dz],        ehswz + eo);                               \
        async_cp16(&EB[dz + 2048], ehswz + eo + 2048);                        \
        async_cp16(&EB[dz + 4096],        elswz + eo);                        \
        async_cp16(&EB[dz + 4096 + 2048], elswz + eo + 2048);                 \
    } while (0)

    STAGE(0, 0);
    STAGE(1, 1);

    float v1[8], v2[8];
    int   i1[8];
#pragma unroll
    for (int s = 0; s < 8; ++s) { v1[s] = -3.4e38f; v2[s] = -3.4e38f; i1[s] = 0; }

    __syncthreads();   // full drain once: chunks 0,1 staged; ESQ visible

    int cur = 0;
#pragma unroll 1
    for (int ch = 0; ch < 16; ++ch) {
        if (ch < 14) STAGE(ch + 2, (cur == 0) ? 2 : cur - 1);   // (cur+2)%3
        const int bz = cur * 8192;
#pragma unroll
        for (int ct = 0; ct < 4; ++ct) {
            const int lc = ct * 16 + col;
            const int x7 = col & 7;
            const int o0 = lc * 64 + (((quad)     ^ x7) << 3);
            const int o1 = lc * 64 + (((quad + 4) ^ x7) << 3);
            short8 BH0 = *(const short8*)&EB[bz + o0];
            short8 BH1 = *(const short8*)&EB[bz + o1];
            short8 BL0 = *(const short8*)&EB[bz + 4096 + o0];
            short8 BL1 = *(const short8*)&EB[bz + 4096 + o1];
            const int code = ch * 64 + lc;
            float eq = ESQ[code];
#pragma unroll
            for (int rt = 0; rt < 2; ++rt) {
                f32x4 acc = {0.f, 0.f, 0.f, 0.f};
                acc = mfma_bf16(AH[rt][0], BH0, acc);
                acc = mfma_bf16(AH[rt][1], BH1, acc);
                acc = mfma_bf16(AH[rt][0], BL0, acc);
                acc = mfma_bf16(AH[rt][1], BL1, acc);
                acc = mfma_bf16(AL[rt][0], BH0, acc);
                acc = mfma_bf16(AL[rt][1], BH1, acc);
#pragma unroll
                for (int reg = 0; reg < 4; ++reg) {
                    const int st = rt * 4 + reg;
                    float sc = fmaf(2.f, acc[reg], -eq);
                    // runner-up: median(sc, v1, v2) == max(v2, min(sc, v1))
                    v2[st] = __builtin_amdgcn_fmed3f(sc, v1[st], v2[st]);
                    bool gt = sc > v1[st];
                    v1[st] = fmaxf(v1[st], sc);
                    i1[st] = gt ? code : i1[st];
                }
            }
        }
        if (ch < 14) {
            asm volatile("s_waitcnt vmcnt(4)" ::: "memory");
            __builtin_amdgcn_s_barrier();
            __builtin_amdgcn_sched_barrier(0);
        } else if (ch < 15) {
            asm volatile("s_waitcnt vmcnt(0)" ::: "memory");
            __builtin_amdgcn_s_barrier();
            __builtin_amdgcn_sched_barrier(0);
        }
        cur = (cur == 2) ? 0 : cur + 1;
    }
#undef STAGE

    // EB is dead now; reuse its first 1.5 KB for the reduction scratch.
    __syncthreads();                       // all waves done reading EB
    int* BIDX   = (int*)&EB[0];            // 128 ints
    int* FLAG   = (int*)&EB[256];          // 128 ints
    int* NFLAGp = (int*)&EB[512];
    if (tid == 0) *NFLAGp = 0;
    __syncthreads();                       // NFLAG=0 visible before atomics

#pragma unroll
    for (int st = 0; st < 8; ++st) {
#pragma unroll
        for (int m = 1; m <= 8; m <<= 1) {
            float ov1 = __shfl_xor(v1[st], m);
            int   oi1 = __shfl_xor(i1[st], m);
            float ov2 = __shfl_xor(v2[st], m);
            float losr = fminf(v1[st], ov1);
            v2[st] = fmaxf(fmaxf(v2[st], ov2), losr);
            bool take = (ov1 > v1[st]) || (ov1 == v1[st] && oi1 < i1[st]);
            v1[st] = take ? ov1 : v1[st];
            i1[st] = take ? oi1 : i1[st];
        }
        if (col == 0) {
            int rt = st >> 2, reg = st & 3;
            int row_l = w * 32 + rt * 16 + quad * 4 + reg;
            BIDX[row_l] = i1[st];
            if (v1[st] - v2[st] < MARGIN) {
                int p = atomicAdd(NFLAGp, 1);
                FLAG[p] = row_l;
            }
        }
    }
    __syncthreads();

    int nf = *NFLAGp;
    for (int i = w; i < nf; i += 4) {
        int row_l = FLAG[i];
        const float* hr = h + (size_t)(r0 + row_l) * 64;
        float accf[16];
#pragma unroll
        for (int j = 0; j < 16; ++j) accf[j] = 0.f;
        for (int d4 = 0; d4 < 16; ++d4) {
            float4 hv = *(const float4*)(hr + d4 * 4);
#pragma unroll
            for (int j = 0; j < 16; ++j) {
                int c = lane + 64 * j;
                float4 ev = *(const float4*)(embed + (size_t)c * 64 + d4 * 4);
                accf[j] += hv.x * ev.x + hv.y * ev.y + hv.z * ev.z + hv.w * ev.w;
            }
        }
        float best = -3.4e38f; int bi = 0;
#pragma unroll
        for (int j = 0; j < 16; ++j) {
            int c = lane + 64 * j;
            float sc = 2.f * accf[j] - ESQ[c];
            if (sc > best) { best = sc; bi = c; }
        }
#pragma unroll
        for (int m = 1; m <= 32; m <<= 1) {
            float ob = __shfl_xor(best, m);
            int  obi = __shfl_xor(bi, m);
            if (ob > best || (ob == best && obi < bi)) { best = ob; bi = obi; }
        }
        if (lane == 0) BIDX[row_l] = bi;
    }
    __syncthreads();

    if (tid < 128) {
        int b = BIDX[tid];
        outIdxF[r0 + tid] = (float)b;
        outIdxI[r0 + tid] = b;
    }
}

// ---------------- GEMM3: out = gather(embed_bf16, idx) @ W_out + b_out ----------------
// Async double-buffered staging via global_load_lds into TRANSPOSED [slot(8)][row(128)]
// LDS (16 B per (slot,row) cell): row is the fast axis, so a fragment read by 64 lanes
// (rows consecutive, slot fixed per quad) hits consecutive 16-B lines -- conflict-free
// with a LINEAR dest (rule 21 satisfied; no padding needed). Q's per-lane global source
// un-XORs the swizzled ehswz row. STAGE(head+1) flies under head's 32 MFMA; one
// __syncthreads per head drains it. Same per-output MFMA sequence as before.
__global__ __launch_bounds__(256) void gemm_out_bf16(const ushort_t* __restrict__ ehswz,
                                                     const int* __restrict__ idx,
                                                     const ushort_t* __restrict__ WbfT,
                                                     const float* __restrict__ bias,
                                                     float* __restrict__ C) {
    __shared__ ushort_t Qs[2][8192];   // [buf][slot*128+row][8] = 16 KB per buf
    __shared__ ushort_t Ws[2][8192];
    __shared__ int idxs[128 * HEADS_]; // 4 KB   (total 68 KB -> 2 blocks/CU, 1024=2x512)

    const int tid  = threadIdx.x;
    const int lane = tid & 63;
    const int w    = tid >> 6;
    const int quad = lane >> 4;
    const int col  = lane & 15;
    const int m0   = blockIdx.y * 128;
    const int n0   = blockIdx.x * 128;
    const int wm   = (w & 1) * 64;
    const int wn   = (w >> 1) * 64;

#pragma unroll
    for (int s = 0; s < 4; ++s) {
        int f = s * 256 + tid;
        idxs[f] = idx[(size_t)m0 * HEADS_ + f];
    }
    __syncthreads();   // idxs visible to all waves before STAGE reads them

    // stage head hd into buf b: wave w covers slots 2w, 2w+1; per (slot, row-half):
    // one gathered Q cp16 (per-lane source, un-XOR) + one regular W cp16.
#define STAGEO(hd, b)                                                         \
    do {                                                                      \
        _Pragma("unroll")                                                     \
        for (int j2 = 0; j2 < 2; ++j2) {                                      \
            const int j = w * 2 + j2;                                         \
            _Pragma("unroll")                                                 \
            for (int r2 = 0; r2 < 2; ++r2) {                                  \
                const int row = r2 * 64 + lane;                               \
                const int e   = idxs[row * HEADS_ + (hd)];                    \
                async_cp16(&Qs[b][(j * 128 + r2 * 64) * 8],                   \
                           ehswz + (size_t)e * 64 + ((j ^ (e & 7)) << 3));    \
                async_cp16(&Ws[b][(j * 128 + r2 * 64) * 8],                   \
                           WbfT + (size_t)(n0 + row) * CBIN_ + (hd)*64 + j*8);\
            }                                                                 \
        }                                                                     \
    } while (0)

    f32x4 acc[4][4];
#pragma unroll
    for (int rt = 0; rt < 4; ++rt)
#pragma unroll
        for (int ct = 0; ct < 4; ++ct) acc[rt][ct] = (f32x4){0.f, 0.f, 0.f, 0.f};

    STAGEO(0, 0);
    __syncthreads();   // head-0 tiles staged (vmcnt drained)

    int b = 0;
#pragma unroll 1
    for (int hd = 0; hd < HEADS_; ++hd) {
        if (hd < 7) STAGEO(hd + 1, b ^ 1);
#pragma unroll
        for (int ks = 0; ks < 2; ++ks) {
            const int sbase = ((ks * 4 + quad) * 128) * 8;
            short8 a[4], bb[4];
#pragma unroll
            for (int rt = 0; rt < 4; ++rt)
                a[rt] = *(const short8*)&Qs[b][sbase + (wm + rt * 16 + col) * 8];
#pragma unroll
            for (int ct = 0; ct < 4; ++ct)
                bb[ct] = *(const short8*)&Ws[b][sbase + (wn + ct * 16 + col) * 8];
#pragma unroll
            for (int rt = 0; rt < 4; ++rt)
#pragma unroll
                for (int ct = 0; ct < 4; ++ct)
                    acc[rt][ct] = mfma_bf16(a[rt], bb[ct], acc[rt][ct]);
        }
        __syncthreads();   // STAGE(hd+1) landed; readers of buf b done before overwrite
        b ^= 1;
    }
#undef STAGEO

#pragma unroll
    for (int ct = 0; ct < 4; ++ct) {
        int gc = n0 + wn + ct * 16 + col;
        float bbias = bias[gc];
#pragma unroll
        for (int rt = 0; rt < 4; ++rt) {
#pragma unroll
            for (int reg = 0; reg < 4; ++reg) {
                int gr = m0 + wm + rt * 16 + quad * 4 + reg;
                C[(size_t)gr * DIM_ + gc] = acc[rt][ct][reg] + bbias;
            }
        }
    }
}

extern "C" void kernel_launch(void* const* d_in, const int* in_sizes, int n_in,
                              void* d_out, int out_size, void* d_ws, size_t ws_size,
                              hipStream_t stream) {
    const float* x     = (const float*)d_in[0];
    const float* W_in  = (const float*)d_in[1];
    const float* b_in  = (const float*)d_in[2];
    const float* W_out = (const float*)d_in[3];
    const float* b_out = (const float*)d_in[4];
    const float* embed = (const float*)d_in[5];

    float* out     = (float*)d_out;
    float* outIdxF = out + (size_t)M_ * DIM_;

    // workspace layout (38.5 MB total)
    char* ws = (char*)d_ws;
    float*    h     = (float*)ws;                                   // 33,554,432 B
    int*      idxI  = (int*)(ws + 33554432);                        //    524,288 B
    float*    esq   = (float*)(ws + 34078720);                      //      4,096 B
    ushort_t* ehswz = (ushort_t*)(ws + 34082816);                   //    131,072 B (swizzled hi)
    ushort_t* elswz = (ushort_t*)(ws + 34213888);                   //    131,072 B (swizzled lo)
    ushort_t* WbfT  = (ushort_t*)(ws + 34344960);                   //  1,048,576 B
    ushort_t* W1T   = (ushort_t*)(ws + 35393536);                   //  1,048,576 B
    ushort_t* W2T   = (ushort_t*)(ws + 36442112);                   //  1,048,576 B
    ushort_t* W3T   = (ushort_t*)(ws + 37490688);                   //  1,048,576 B

    esq_kernel<<<dim3(CBS_ / 256), dim3(256), 0, stream>>>(embed, esq);
    split_embed<<<dim3(CBS_ * CBD_ / 256), dim3(256), 0, stream>>>(embed, ehswz, elswz);
    transposeW<<<dim3(DIM_ / 64, CBIN_ / 64), dim3(256), 0, stream>>>(W_out, WbfT);
    split_WinT<<<dim3(CBIN_ / 64, DIM_ / 64), dim3(256), 0, stream>>>(W_in, W1T, W2T, W3T);
    gemm_in_x6<<<dim3(CBIN_ / 128, M_ / 128), dim3(512), 0, stream>>>(x, W1T, W2T, W3T,
                                                                      b_in, h);
    argmax2<<<dim3(M2_ / 128), dim3(256), 0, stream>>>(h, ehswz, elswz, esq, embed,
                                                       outIdxF, idxI);
    gemm_out_bf16<<<dim3(DIM_ / 128, M_ / 128), dim3(256), 0, stream>>>(ehswz, idxI, WbfT,
                                                                        b_out, out);
}

// Round 9
// 356.463 us; speedup vs baseline: 2.0716x; 1.0392x over previous
//
#include <hip/hip_runtime.h>

#define B_      8
#define N_      2048
#define DIM_    1024
#define HEADS_  8
#define CBD_    64
#define CBS_    1024
#define CBIN_   512              // HEADS_*CBD_
#define M_      (B_*N_)          // 16384 rows
#define M2_     (M_*HEADS_)      // 131072 row-heads

#define MARGIN 0.02f             // >> deterministic bf16x3 score error bound (~2.4e-3)
#define XSTR   40                // LDS stride (elements) for 32-k bf16 planes; 80 B = 16-B aligned

typedef unsigned short ushort_t;
typedef __attribute__((ext_vector_type(8))) short short8;
typedef __attribute__((ext_vector_type(4))) float f32x4;

__device__ inline ushort_t f2bf(float f) {
    unsigned int u = __builtin_bit_cast(unsigned int, f);
    unsigned int r = u + 0x7FFFu + ((u >> 16) & 1u);
    return (ushort_t)(r >> 16);
}
__device__ inline float bf2f(ushort_t h) {
    unsigned int u = ((unsigned int)h) << 16;
    return __builtin_bit_cast(float, u);
}
__device__ inline f32x4 mfma_bf16(short8 a, short8 b, f32x4 c) {
    return __builtin_amdgcn_mfma_f32_16x16x32_bf16(a, b, c, 0, 0, 0);
}
__device__ inline void store4u(ushort_t* p, ushort_t a, ushort_t b, ushort_t c, ushort_t d) {
    uint2 u;
    u.x = (unsigned int)a | ((unsigned int)b << 16);
    u.y = (unsigned int)c | ((unsigned int)d << 16);
    *(uint2*)p = u;
}
// 3-way bf16 split: f = s1 + s2 + s3 + O(2^-24 |f|)
__device__ inline void split3(float f, ushort_t& s1, ushort_t& s2, ushort_t& s3) {
    s1 = f2bf(f);
    float r = f - bf2f(s1);
    s2 = f2bf(r);
    float r2 = r - bf2f(s2);
    s3 = f2bf(r2);
}
// async 16-B global -> LDS (dest is wave-uniform base; HW adds lane*16)
__device__ inline void async_cp16(void* lds, const void* g) {
    __builtin_amdgcn_global_load_lds(
        (const __attribute__((address_space(1))) unsigned int*)g,
        (__attribute__((address_space(3))) unsigned int*)lds, 16, 0, 0);
}

// ---------------- prep: esq[c] = sum_d embed[c][d]^2 (fp32) ----------------
__global__ __launch_bounds__(256) void esq_kernel(const float* __restrict__ embed,
                                                  float* __restrict__ esq) {
    int c = blockIdx.x * 256 + threadIdx.x;
    if (c < CBS_) {
        const float* e = embed + (size_t)c * CBD_;
        float s = 0.f;
#pragma unroll
        for (int d = 0; d < CBD_; ++d) s += e[d] * e[d];
        esq[c] = s;
    }
}

// ---------------- prep: split embed into bf16 hi/lo, XOR-SWIZZLED layout ----------------
// Within each 128-B code row, 16-B slot s lands at slot s ^ (code&7). argmax2 reads it
// with the matching XOR; gemm_out's gather un-XORs per-lane on the global source.
__global__ __launch_bounds__(256) void split_embed(const float* __restrict__ embed,
                                                   ushort_t* __restrict__ hi,
                                                   ushort_t* __restrict__ lo) {
    int i = blockIdx.x * 256 + threadIdx.x;   // 65536 total
    int code = i >> 6, d = i & 63;
    int dst = code * 64 + ((((d >> 3) ^ (code & 7)) << 3) | (d & 7));
    float f = embed[i];
    ushort_t hh = f2bf(f);
    hi[dst] = hh;
    lo[dst] = f2bf(f - bf2f(hh));
}

// ---------------- prep: WbfT[n][k] = bf16(W_out[k][n]) ----------------
__global__ __launch_bounds__(256) void transposeW(const float* __restrict__ W,
                                                  ushort_t* __restrict__ WT) {
    __shared__ ushort_t t[64][65];
    const int tid = threadIdx.x;
    const int n0 = blockIdx.x * 64, k0 = blockIdx.y * 64;
#pragma unroll
    for (int s = 0; s < 16; ++s) {
        int i = s * 256 + tid;
        int r = i >> 6, c = i & 63;
        t[r][c] = f2bf(W[(size_t)(k0 + r) * DIM_ + n0 + c]);
    }
    __syncthreads();
#pragma unroll
    for (int s = 0; s < 16; ++s) {
        int i = s * 256 + tid;
        int r = i >> 6, c = i & 63;
        WT[(size_t)(n0 + r) * CBIN_ + k0 + c] = t[c][r];
    }
}

// ---------------- prep: 3-way split + transpose of W_in: WpT[n][k] ----------------
__global__ __launch_bounds__(256) void split_WinT(const float* __restrict__ W,
                                                  ushort_t* __restrict__ W1T,
                                                  ushort_t* __restrict__ W2T,
                                                  ushort_t* __restrict__ W3T) {
    __shared__ ushort_t t1[64][65];
    __shared__ ushort_t t2[64][65];
    __shared__ ushort_t t3[64][65];
    const int tid = threadIdx.x;
    const int n0 = blockIdx.x * 64, k0 = blockIdx.y * 64;
#pragma unroll
    for (int s = 0; s < 16; ++s) {
        int i = s * 256 + tid;
        int r = i >> 6, c = i & 63;                 // r = k in tile, c = n in tile
        float f = W[(size_t)(k0 + r) * CBIN_ + n0 + c];
        split3(f, t1[r][c], t2[r][c], t3[r][c]);
    }
    __syncthreads();
#pragma unroll
    for (int s = 0; s < 16; ++s) {
        int i = s * 256 + tid;
        int r = i >> 6, c = i & 63;                 // r = n in tile, c = k in tile
        size_t o = (size_t)(n0 + r) * DIM_ + k0 + c;
        W1T[o] = t1[c][r];
        W2T[o] = t2[c][r];
        W3T[o] = t3[c][r];
    }
}

// ---------------- GEMM1 via bf16x6 MFMA: h[M,512] = x @ W_in + b_in ----------------
// Round-5 version (proven): 128x128 tile, BK=32, 8 waves, wave tile 64x32, XCD swizzle.
__global__ __launch_bounds__(512) void gemm_in_x6(const float* __restrict__ x,
                                                  const ushort_t* __restrict__ W1T,
                                                  const ushort_t* __restrict__ W2T,
                                                  const ushort_t* __restrict__ W3T,
                                                  const float* __restrict__ bias,
                                                  float* __restrict__ C) {
    __shared__ ushort_t A1[128 * XSTR];
    __shared__ ushort_t A2[128 * XSTR];
    __shared__ ushort_t A3[128 * XSTR];
    __shared__ ushort_t B1[128 * XSTR];
    __shared__ ushort_t B2[128 * XSTR];
    __shared__ ushort_t B3[128 * XSTR];   // 6 * 10240 B = 61440 B

    const int tid  = threadIdx.x;
    const int lane = tid & 63;
    const int w    = tid >> 6;            // 0..7
    const int quad = lane >> 4;
    const int col  = lane & 15;

    const int slot   = blockIdx.y * 4 + blockIdx.x;   // dispatch order, x fastest
    const int g      = slot & 7;
    const int t      = slot >> 3;
    const int m0     = (g + 8 * (t >> 2)) * 128;
    const int n0     = (t & 3) * 128;

    const int wm   = (w & 1) * 64;        // 2 row groups of 64
    const int wn   = (w >> 1) * 32;       // 4 col groups of 32

    f32x4 acc[4][2];
#pragma unroll
    for (int rt = 0; rt < 4; ++rt)
#pragma unroll
        for (int ct = 0; ct < 2; ++ct) acc[rt][ct] = (f32x4){0.f, 0.f, 0.f, 0.f};

    for (int k0 = 0; k0 < DIM_; k0 += 32) {
        __syncthreads();
#pragma unroll
        for (int s = 0; s < 2; ++s) {
            int f = s * 512 + tid;
            int row = f >> 3, qq = f & 7;
            float4 v = *(const float4*)(x + (size_t)(m0 + row) * DIM_ + k0 + qq * 4);
            float vv[4] = {v.x, v.y, v.z, v.w};
            ushort_t p1[4], p2[4], p3[4];
#pragma unroll
            for (int j = 0; j < 4; ++j) split3(vv[j], p1[j], p2[j], p3[j]);
            int base = row * XSTR + qq * 4;
            store4u(&A1[base], p1[0], p1[1], p1[2], p1[3]);
            store4u(&A2[base], p2[0], p2[1], p2[2], p2[3]);
            store4u(&A3[base], p3[0], p3[1], p3[2], p3[3]);
        }
        {
            int row = tid >> 2, g2 = tid & 3;
            size_t go = (size_t)(n0 + row) * DIM_ + k0 + g2 * 8;
            int lo = row * XSTR + g2 * 8;
            *(uint4*)&B1[lo] = *(const uint4*)(W1T + go);
            *(uint4*)&B2[lo] = *(const uint4*)(W2T + go);
            *(uint4*)&B3[lo] = *(const uint4*)(W3T + go);
        }
        __syncthreads();

        short8 a1[4], a2[4], a3[4], b1[2], b2[2], b3[2];
#pragma unroll
        for (int rt = 0; rt < 4; ++rt) {
            int o = (wm + rt * 16 + col) * XSTR + quad * 8;
            a1[rt] = *(const short8*)&A1[o];
            a2[rt] = *(const short8*)&A2[o];
            a3[rt] = *(const short8*)&A3[o];
        }
#pragma unroll
        for (int ct = 0; ct < 2; ++ct) {
            int o = (wn + ct * 16 + col) * XSTR + quad * 8;
            b1[ct] = *(const short8*)&B1[o];
            b2[ct] = *(const short8*)&B2[o];
            b3[ct] = *(const short8*)&B3[o];
        }
#define COMBO(AP, BP)                                                   \
        _Pragma("unroll")                                               \
        for (int ct = 0; ct < 2; ++ct)                                  \
            _Pragma("unroll")                                           \
            for (int rt = 0; rt < 4; ++rt)                              \
                acc[rt][ct] = mfma_bf16(AP[rt], BP[ct], acc[rt][ct]);
        COMBO(a1, b1); COMBO(a1, b2); COMBO(a2, b1);
        COMBO(a2, b2); COMBO(a1, b3); COMBO(a3, b1);
#undef COMBO
    }

#pragma unroll
    for (int ct = 0; ct < 2; ++ct) {
        int gc = n0 + wn + ct * 16 + col;
        float bb = bias[gc];
#pragma unroll
        for (int rt = 0; rt < 4; ++rt) {
#pragma unroll
            for (int reg = 0; reg < 4; ++reg) {
                int gr = m0 + wm + rt * 16 + quad * 4 + reg;
                C[(size_t)gr * CBIN_ + gc] = acc[rt][ct][reg] + bb;
            }
        }
    }
}

// ---------------- argmax: A in regs, B async double-buffered in LDS ----------------
// ROUND-5 VERSION VERBATIM -- PROTECTED LOCAL OPTIMUM (118.7 us, 64 VGPR, 4 blocks/CU,
// zero scratch). Evidence ledger: chain-split/+8 VGPR => catastrophic spill (R3/R4);
// full unroll of ch loop => 256 VGPR + 770 MB scratch (R7); triple-buffer counted-vmcnt
// => LDS 53 KB drops residency to 3 blocks/CU, dur 169 us (R8). The 4th resident block
// is worth more than any barrier-drain saving. DO NOT grow LDS or live VGPRs here.
__global__ __launch_bounds__(256, 4) void argmax2(const float* __restrict__ h,
                                                  const ushort_t* __restrict__ ehswz,
                                                  const ushort_t* __restrict__ elswz,
                                                  const float* __restrict__ esq,
                                                  const float* __restrict__ embed,
                                                  float* __restrict__ outIdxF,
                                                  int* __restrict__ outIdxI) {
    __shared__ ushort_t EB[2][2][4096];   // [buf][hi/lo][64 codes * 64 elems] = 32 KB
    __shared__ float    ESQ[CBS_];
    __shared__ int BIDX[128];
    __shared__ int FLAG[128];
    __shared__ int NFLAG;

    const int tid  = threadIdx.x;
    const int lane = tid & 63;
    const int w    = tid >> 6;
    const int quad = lane >> 4;
    const int col  = lane & 15;
    const int r0   = blockIdx.x * 128;

    if (tid == 0) NFLAG = 0;
    *(float4*)&ESQ[tid * 4] = *(const float4*)(esq + tid * 4);

    // A fragments: wave reads 16 contiguous rows x 256 B, split hi/lo in regs
    short8 AH[2][2], AL[2][2];
#pragma unroll
    for (int rt = 0; rt < 2; ++rt) {
        const float* hp = h + (size_t)(r0 + w * 32 + rt * 16 + col) * 64 + quad * 8;
#pragma unroll
        for (int ks = 0; ks < 2; ++ks) {
            float4 u0 = *(const float4*)(hp + ks * 32);
            float4 u1 = *(const float4*)(hp + ks * 32 + 4);
            float vv[8] = {u0.x, u0.y, u0.z, u0.w, u1.x, u1.y, u1.z, u1.w};
            short8 hh, ll;
#pragma unroll
            for (int j = 0; j < 8; ++j) {
                ushort_t hi = f2bf(vv[j]);
                hh[j] = (short)hi;
                ll[j] = (short)f2bf(vv[j] - bf2f(hi));
            }
            AH[rt][ks] = hh;
            AL[rt][ks] = ll;
        }
    }

    // stage: 4 async 16-B copies per chunk (hi/lo x two 4-KB slices); dest wave-uniform
#define STAGE(ch, b)                                                          \
    do {                                                                      \
        int eo = (ch) * 4096 + tid * 8;                                       \
        int wo = w * 512;                                                     \
        async_cp16(&EB[b][0][wo],        ehswz + eo);                         \
        async_cp16(&EB[b][0][2048 + wo], ehswz + eo + 2048);                  \
        async_cp16(&EB[b][1][wo],        elswz + eo);                         \
        async_cp16(&EB[b][1][2048 + wo], elswz + eo + 2048);                  \
    } while (0)

    STAGE(0, 0);

    float v1[8], v2[8];
    int   i1[8];
#pragma unroll
    for (int s = 0; s < 8; ++s) { v1[s] = -3.4e38f; v2[s] = -3.4e38f; i1[s] = 0; }

    __syncthreads();   // chunk0 staged (vmcnt drained), ESQ + NFLAG visible

    int cur = 0;
    for (int ch = 0; ch < 16; ++ch) {
        if (ch < 15) STAGE(ch + 1, cur ^ 1);
#pragma unroll
        for (int ct = 0; ct < 4; ++ct) {
            const int lc = ct * 16 + col;
            const int x7 = col & 7;
            const int o0 = lc * 64 + (((quad)     ^ x7) << 3);
            const int o1 = lc * 64 + (((quad + 4) ^ x7) << 3);
            short8 BH0 = *(const short8*)&EB[cur][0][o0];
            short8 BH1 = *(const short8*)&EB[cur][0][o1];
            short8 BL0 = *(const short8*)&EB[cur][1][o0];
            short8 BL1 = *(const short8*)&EB[cur][1][o1];
            const int code = ch * 64 + lc;
            float eq = ESQ[code];
#pragma unroll
            for (int rt = 0; rt < 2; ++rt) {
                f32x4 acc = {0.f, 0.f, 0.f, 0.f};
                acc = mfma_bf16(AH[rt][0], BH0, acc);
                acc = mfma_bf16(AH[rt][1], BH1, acc);
                acc = mfma_bf16(AH[rt][0], BL0, acc);
                acc = mfma_bf16(AH[rt][1], BL1, acc);
                acc = mfma_bf16(AL[rt][0], BH0, acc);
                acc = mfma_bf16(AL[rt][1], BH1, acc);
#pragma unroll
                for (int reg = 0; reg < 4; ++reg) {
                    const int st = rt * 4 + reg;
                    float sc = fmaf(2.f, acc[reg], -eq);
                    // runner-up: median(sc, v1, v2) == max(v2, min(sc, v1))
                    v2[st] = __builtin_amdgcn_fmed3f(sc, v1[st], v2[st]);
                    bool gt = sc > v1[st];
                    v1[st] = fmaxf(v1[st], sc);
                    i1[st] = gt ? code : i1[st];
                }
            }
        }
        __syncthreads();   // staging of ch+1 complete; all waves done reading buf cur
        cur ^= 1;
    }
#undef STAGE

#pragma unroll
    for (int st = 0; st < 8; ++st) {
#pragma unroll
        for (int m = 1; m <= 8; m <<= 1) {
            float ov1 = __shfl_xor(v1[st], m);
            int   oi1 = __shfl_xor(i1[st], m);
            float ov2 = __shfl_xor(v2[st], m);
            float losr = fminf(v1[st], ov1);
            v2[st] = fmaxf(fmaxf(v2[st], ov2), losr);
            bool take = (ov1 > v1[st]) || (ov1 == v1[st] && oi1 < i1[st]);
            v1[st] = take ? ov1 : v1[st];
            i1[st] = take ? oi1 : i1[st];
        }
        if (col == 0) {
            int rt = st >> 2, reg = st & 3;
            int row_l = w * 32 + rt * 16 + quad * 4 + reg;
            BIDX[row_l] = i1[st];
            if (v1[st] - v2[st] < MARGIN) {
                int p = atomicAdd(&NFLAG, 1);
                FLAG[p] = row_l;
            }
        }
    }
    __syncthreads();

    int nf = NFLAG;
    for (int i = w; i < nf; i += 4) {
        int row_l = FLAG[i];
        const float* hr = h + (size_t)(r0 + row_l) * 64;
        float accf[16];
#pragma unroll
        for (int j = 0; j < 16; ++j) accf[j] = 0.f;
        for (int d4 = 0; d4 < 16; ++d4) {
            float4 hv = *(const float4*)(hr + d4 * 4);
#pragma unroll
            for (int j = 0; j < 16; ++j) {
                int c = lane + 64 * j;
                float4 ev = *(const float4*)(embed + (size_t)c * 64 + d4 * 4);
                accf[j] += hv.x * ev.x + hv.y * ev.y + hv.z * ev.z + hv.w * ev.w;
            }
        }
        float best = -3.4e38f; int bi = 0;
#pragma unroll
        for (int j = 0; j < 16; ++j) {
            int c = lane + 64 * j;
            float sc = 2.f * accf[j] - ESQ[c];
            if (sc > best) { best = sc; bi = c; }
        }
#pragma unroll
        for (int m = 1; m <= 32; m <<= 1) {
            float ob = __shfl_xor(best, m);
            int  obi = __shfl_xor(bi, m);
            if (ob > best || (ob == best && obi < bi)) { best = ob; bi = obi; }
        }
        if (lane == 0) BIDX[row_l] = bi;
    }
    __syncthreads();

    if (tid < 128) {
        int b = BIDX[tid];
        outIdxF[r0 + tid] = (float)b;
        outIdxI[r0 + tid] = b;
    }
}

// ---------------- GEMM3: out = gather(embed_bf16, idx) @ W_out + b_out ----------------
// ROUND-8 VERSION (proven ~46 us faster than the sync-staged variant). Async double-
// buffered staging via global_load_lds into TRANSPOSED [slot(8)][row(128)] LDS (16 B
// per (slot,row) cell): row is the fast axis -> conflict-free with a LINEAR dest.
// Q's per-lane global source un-XORs the swizzled ehswz row. STAGE(head+1) flies under
// head's 32 MFMA; one __syncthreads per head drains it.
__global__ __launch_bounds__(256) void gemm_out_bf16(const ushort_t* __restrict__ ehswz,
                                                     const int* __restrict__ idx,
                                                     const ushort_t* __restrict__ WbfT,
                                                     const float* __restrict__ bias,
                                                     float* __restrict__ C) {
    __shared__ ushort_t Qs[2][8192];   // [buf][slot*128+row][8] = 16 KB per buf
    __shared__ ushort_t Ws[2][8192];
    __shared__ int idxs[128 * HEADS_]; // 4 KB

    const int tid  = threadIdx.x;
    const int lane = tid & 63;
    const int w    = tid >> 6;
    const int quad = lane >> 4;
    const int col  = lane & 15;
    const int m0   = blockIdx.y * 128;
    const int n0   = blockIdx.x * 128;
    const int wm   = (w & 1) * 64;
    const int wn   = (w >> 1) * 64;

#pragma unroll
    for (int s = 0; s < 4; ++s) {
        int f = s * 256 + tid;
        idxs[f] = idx[(size_t)m0 * HEADS_ + f];
    }
    __syncthreads();   // idxs visible to all waves before STAGE reads them

    // stage head hd into buf b: wave w covers slots 2w, 2w+1; per (slot, row-half):
    // one gathered Q cp16 (per-lane source, un-XOR) + one regular W cp16.
#define STAGEO(hd, b)                                                         \
    do {                                                                      \
        _Pragma("unroll")                                                     \
        for (int j2 = 0; j2 < 2; ++j2) {                                      \
            const int j = w * 2 + j2;                                         \
            _Pragma("unroll")                                                 \
            for (int r2 = 0; r2 < 2; ++r2) {                                  \
                const int row = r2 * 64 + lane;                               \
                const int e   = idxs[row * HEADS_ + (hd)];                    \
                async_cp16(&Qs[b][(j * 128 + r2 * 64) * 8],                   \
                           ehswz + (size_t)e * 64 + ((j ^ (e & 7)) << 3));    \
                async_cp16(&Ws[b][(j * 128 + r2 * 64) * 8],                   \
                           WbfT + (size_t)(n0 + row) * CBIN_ + (hd)*64 + j*8);\
            }                                                                 \
        }                                                                     \
    } while (0)

    f32x4 acc[4][4];
#pragma unroll
    for (int rt = 0; rt < 4; ++rt)
#pragma unroll
        for (int ct = 0; ct < 4; ++ct) acc[rt][ct] = (f32x4){0.f, 0.f, 0.f, 0.f};

    STAGEO(0, 0);
    __syncthreads();   // head-0 tiles staged (vmcnt drained)

    int b = 0;
#pragma unroll 1
    for (int hd = 0; hd < HEADS_; ++hd) {
        if (hd < 7) STAGEO(hd + 1, b ^ 1);
#pragma unroll
        for (int ks = 0; ks < 2; ++ks) {
            const int sbase = ((ks * 4 + quad) * 128) * 8;
            short8 a[4], bb[4];
#pragma unroll
            for (int rt = 0; rt < 4; ++rt)
                a[rt] = *(const short8*)&Qs[b][sbase + (wm + rt * 16 + col) * 8];
#pragma unroll
            for (int ct = 0; ct < 4; ++ct)
                bb[ct] = *(const short8*)&Ws[b][sbase + (wn + ct * 16 + col) * 8];
#pragma unroll
            for (int rt = 0; rt < 4; ++rt)
#pragma unroll
                for (int ct = 0; ct < 4; ++ct)
                    acc[rt][ct] = mfma_bf16(a[rt], bb[ct], acc[rt][ct]);
        }
        __syncthreads();   // STAGE(hd+1) landed; readers of buf b done before overwrite
        b ^= 1;
    }
#undef STAGEO

#pragma unroll
    for (int ct = 0; ct < 4; ++ct) {
        int gc = n0 + wn + ct * 16 + col;
        float bbias = bias[gc];
#pragma unroll
        for (int rt = 0; rt < 4; ++rt) {
#pragma unroll
            for (int reg = 0; reg < 4; ++reg) {
                int gr = m0 + wm + rt * 16 + quad * 4 + reg;
                C[(size_t)gr * DIM_ + gc] = acc[rt][ct][reg] + bbias;
            }
        }
    }
}

extern "C" void kernel_launch(void* const* d_in, const int* in_sizes, int n_in,
                              void* d_out, int out_size, void* d_ws, size_t ws_size,
                              hipStream_t stream) {
    const float* x     = (const float*)d_in[0];
    const float* W_in  = (const float*)d_in[1];
    const float* b_in  = (const float*)d_in[2];
    const float* W_out = (const float*)d_in[3];
    const float* b_out = (const float*)d_in[4];
    const float* embed = (const float*)d_in[5];

    float* out     = (float*)d_out;
    float* outIdxF = out + (size_t)M_ * DIM_;

    // workspace layout (38.5 MB total)
    char* ws = (char*)d_ws;
    float*    h     = (float*)ws;                                   // 33,554,432 B
    int*      idxI  = (int*)(ws + 33554432);                        //    524,288 B
    float*    esq   = (float*)(ws + 34078720);                      //      4,096 B
    ushort_t* ehswz = (ushort_t*)(ws + 34082816);                   //    131,072 B (swizzled hi)
    ushort_t* elswz = (ushort_t*)(ws + 34213888);                   //    131,072 B (swizzled lo)
    ushort_t* WbfT  = (ushort_t*)(ws + 34344960);                   //  1,048,576 B
    ushort_t* W1T   = (ushort_t*)(ws + 35393536);                   //  1,048,576 B
    ushort_t* W2T   = (ushort_t*)(ws + 36442112);                   //  1,048,576 B
    ushort_t* W3T   = (ushort_t*)(ws + 37490688);                   //  1,048,576 B

    esq_kernel<<<dim3(CBS_ / 256), dim3(256), 0, stream>>>(embed, esq);
    split_embed<<<dim3(CBS_ * CBD_ / 256), dim3(256), 0, stream>>>(embed, ehswz, elswz);
    transposeW<<<dim3(DIM_ / 64, CBIN_ / 64), dim3(256), 0, stream>>>(W_out, WbfT);
    split_WinT<<<dim3(CBIN_ / 64, DIM_ / 64), dim3(256), 0, stream>>>(W_in, W1T, W2T, W3T);
    gemm_in_x6<<<dim3(CBIN_ / 128, M_ / 128), dim3(512), 0, stream>>>(x, W1T, W2T, W3T,
                                                                      b_in, h);
    argmax2<<<dim3(M2_ / 128), dim3(256), 0, stream>>>(h, ehswz, elswz, esq, embed,
                                                       outIdxF, idxI);
    gemm_out_bf16<<<dim3(DIM_ / 128, M_ / 128), dim3(256), 0, stream>>>(ehswz, idxI, WbfT,
                                                                        b_out, out);
}

// Round 10
// 346.463 us; speedup vs baseline: 2.1314x; 1.0289x over previous
//
#include <hip/hip_runtime.h>

#define B_      8
#define N_      2048
#define DIM_    1024
#define HEADS_  8
#define CBD_    64
#define CBS_    1024
#define CBIN_   512              // HEADS_*CBD_
#define M_      (B_*N_)          // 16384 rows
#define M2_     (M_*HEADS_)      // 131072 row-heads

#define MARGIN 0.02f             // >> deterministic bf16x3 score error bound (~2.4e-3)
#define XSTR   40                // LDS stride (elements) for 32-k bf16 planes; 80 B = 16-B aligned

typedef unsigned short ushort_t;
typedef __attribute__((ext_vector_type(8))) short short8;
typedef __attribute__((ext_vector_type(4))) float f32x4;

__device__ inline ushort_t f2bf(float f) {
    unsigned int u = __builtin_bit_cast(unsigned int, f);
    unsigned int r = u + 0x7FFFu + ((u >> 16) & 1u);
    return (ushort_t)(r >> 16);
}
__device__ inline float bf2f(ushort_t h) {
    unsigned int u = ((unsigned int)h) << 16;
    return __builtin_bit_cast(float, u);
}
__device__ inline f32x4 mfma_bf16(short8 a, short8 b, f32x4 c) {
    return __builtin_amdgcn_mfma_f32_16x16x32_bf16(a, b, c, 0, 0, 0);
}
__device__ inline void store4u(ushort_t* p, ushort_t a, ushort_t b, ushort_t c, ushort_t d) {
    uint2 u;
    u.x = (unsigned int)a | ((unsigned int)b << 16);
    u.y = (unsigned int)c | ((unsigned int)d << 16);
    *(uint2*)p = u;
}
// 3-way bf16 split: f = s1 + s2 + s3 + O(2^-24 |f|)
__device__ inline void split3(float f, ushort_t& s1, ushort_t& s2, ushort_t& s3) {
    s1 = f2bf(f);
    float r = f - bf2f(s1);
    s2 = f2bf(r);
    float r2 = r - bf2f(s2);
    s3 = f2bf(r2);
}
// async 16-B global -> LDS (dest is wave-uniform base; HW adds lane*16)
__device__ inline void async_cp16(void* lds, const void* g) {
    __builtin_amdgcn_global_load_lds(
        (const __attribute__((address_space(1))) unsigned int*)g,
        (__attribute__((address_space(3))) unsigned int*)lds, 16, 0, 0);
}

// ------- prep: fused esq + split: hi/lo XOR-swizzled bf16 planes + esq[c] -----------
// Same element embed[i] feeds both outputs. esq via 64-lane shuffle-reduce (association
// differs from a serial loop by ulps only; used consistently in argmax2 + its fallback).
__global__ __launch_bounds__(256) void prep_embed(const float* __restrict__ embed,
                                                  ushort_t* __restrict__ hi,
                                                  ushort_t* __restrict__ lo,
                                                  float* __restrict__ esq) {
    int i = blockIdx.x * 256 + threadIdx.x;   // 65536 total
    int code = i >> 6, d = i & 63;
    float f = embed[i];
    int dst = code * 64 + ((((d >> 3) ^ (code & 7)) << 3) | (d & 7));
    ushort_t hh = f2bf(f);
    hi[dst] = hh;
    lo[dst] = f2bf(f - bf2f(hh));
    float s = f * f;
#pragma unroll
    for (int m = 1; m <= 32; m <<= 1) s += __shfl_xor(s, m);
    if (d == 0) esq[code] = s;
}

// ---------------- prep: WbfT[n][k] = bf16(W_out[k][n]) ----------------
__global__ __launch_bounds__(256) void transposeW(const float* __restrict__ W,
                                                  ushort_t* __restrict__ WT) {
    __shared__ ushort_t t[64][65];
    const int tid = threadIdx.x;
    const int n0 = blockIdx.x * 64, k0 = blockIdx.y * 64;
#pragma unroll
    for (int s = 0; s < 16; ++s) {
        int i = s * 256 + tid;
        int r = i >> 6, c = i & 63;
        t[r][c] = f2bf(W[(size_t)(k0 + r) * DIM_ + n0 + c]);
    }
    __syncthreads();
#pragma unroll
    for (int s = 0; s < 16; ++s) {
        int i = s * 256 + tid;
        int r = i >> 6, c = i & 63;
        WT[(size_t)(n0 + r) * CBIN_ + k0 + c] = t[c][r];
    }
}

// ---------------- prep: 3-way split + transpose of W_in: WpT[n][k] ----------------
__global__ __launch_bounds__(256) void split_WinT(const float* __restrict__ W,
                                                  ushort_t* __restrict__ W1T,
                                                  ushort_t* __restrict__ W2T,
                                                  ushort_t* __restrict__ W3T) {
    __shared__ ushort_t t1[64][65];
    __shared__ ushort_t t2[64][65];
    __shared__ ushort_t t3[64][65];
    const int tid = threadIdx.x;
    const int n0 = blockIdx.x * 64, k0 = blockIdx.y * 64;
#pragma unroll
    for (int s = 0; s < 16; ++s) {
        int i = s * 256 + tid;
        int r = i >> 6, c = i & 63;                 // r = k in tile, c = n in tile
        float f = W[(size_t)(k0 + r) * CBIN_ + n0 + c];
        split3(f, t1[r][c], t2[r][c], t3[r][c]);
    }
    __syncthreads();
#pragma unroll
    for (int s = 0; s < 16; ++s) {
        int i = s * 256 + tid;
        int r = i >> 6, c = i & 63;                 // r = n in tile, c = k in tile
        size_t o = (size_t)(n0 + r) * DIM_ + k0 + c;
        W1T[o] = t1[c][r];
        W2T[o] = t2[c][r];
        W3T[o] = t3[c][r];
    }
}

// ---------------- GEMM1 via bf16x6 MFMA: h[M,512] = x @ W_in + b_in ----------------
// Round-5 version (proven): 128x128 tile, BK=32, 8 waves, wave tile 64x32, XCD swizzle.
__global__ __launch_bounds__(512) void gemm_in_x6(const float* __restrict__ x,
                                                  const ushort_t* __restrict__ W1T,
                                                  const ushort_t* __restrict__ W2T,
                                                  const ushort_t* __restrict__ W3T,
                                                  const float* __restrict__ bias,
                                                  float* __restrict__ C) {
    __shared__ ushort_t A1[128 * XSTR];
    __shared__ ushort_t A2[128 * XSTR];
    __shared__ ushort_t A3[128 * XSTR];
    __shared__ ushort_t B1[128 * XSTR];
    __shared__ ushort_t B2[128 * XSTR];
    __shared__ ushort_t B3[128 * XSTR];   // 6 * 10240 B = 61440 B

    const int tid  = threadIdx.x;
    const int lane = tid & 63;
    const int w    = tid >> 6;            // 0..7
    const int quad = lane >> 4;
    const int col  = lane & 15;

    const int slot   = blockIdx.y * 4 + blockIdx.x;   // dispatch order, x fastest
    const int g      = slot & 7;
    const int t      = slot >> 3;
    const int m0     = (g + 8 * (t >> 2)) * 128;
    const int n0     = (t & 3) * 128;

    const int wm   = (w & 1) * 64;        // 2 row groups of 64
    const int wn   = (w >> 1) * 32;       // 4 col groups of 32

    f32x4 acc[4][2];
#pragma unroll
    for (int rt = 0; rt < 4; ++rt)
#pragma unroll
        for (int ct = 0; ct < 2; ++ct) acc[rt][ct] = (f32x4){0.f, 0.f, 0.f, 0.f};

    for (int k0 = 0; k0 < DIM_; k0 += 32) {
        __syncthreads();
#pragma unroll
        for (int s = 0; s < 2; ++s) {
            int f = s * 512 + tid;
            int row = f >> 3, qq = f & 7;
            float4 v = *(const float4*)(x + (size_t)(m0 + row) * DIM_ + k0 + qq * 4);
            float vv[4] = {v.x, v.y, v.z, v.w};
            ushort_t p1[4], p2[4], p3[4];
#pragma unroll
            for (int j = 0; j < 4; ++j) split3(vv[j], p1[j], p2[j], p3[j]);
            int base = row * XSTR + qq * 4;
            store4u(&A1[base], p1[0], p1[1], p1[2], p1[3]);
            store4u(&A2[base], p2[0], p2[1], p2[2], p2[3]);
            store4u(&A3[base], p3[0], p3[1], p3[2], p3[3]);
        }
        {
            int row = tid >> 2, g2 = tid & 3;
            size_t go = (size_t)(n0 + row) * DIM_ + k0 + g2 * 8;
            int lo = row * XSTR + g2 * 8;
            *(uint4*)&B1[lo] = *(const uint4*)(W1T + go);
            *(uint4*)&B2[lo] = *(const uint4*)(W2T + go);
            *(uint4*)&B3[lo] = *(const uint4*)(W3T + go);
        }
        __syncthreads();

        short8 a1[4], a2[4], a3[4], b1[2], b2[2], b3[2];
#pragma unroll
        for (int rt = 0; rt < 4; ++rt) {
            int o = (wm + rt * 16 + col) * XSTR + quad * 8;
            a1[rt] = *(const short8*)&A1[o];
            a2[rt] = *(const short8*)&A2[o];
            a3[rt] = *(const short8*)&A3[o];
        }
#pragma unroll
        for (int ct = 0; ct < 2; ++ct) {
            int o = (wn + ct * 16 + col) * XSTR + quad * 8;
            b1[ct] = *(const short8*)&B1[o];
            b2[ct] = *(const short8*)&B2[o];
            b3[ct] = *(const short8*)&B3[o];
        }
#define COMBO(AP, BP)                                                   \
        _Pragma("unroll")                                               \
        for (int ct = 0; ct < 2; ++ct)                                  \
            _Pragma("unroll")                                           \
            for (int rt = 0; rt < 4; ++rt)                              \
                acc[rt][ct] = mfma_bf16(AP[rt], BP[ct], acc[rt][ct]);
        COMBO(a1, b1); COMBO(a1, b2); COMBO(a2, b1);
        COMBO(a2, b2); COMBO(a1, b3); COMBO(a3, b1);
#undef COMBO
    }

#pragma unroll
    for (int ct = 0; ct < 2; ++ct) {
        int gc = n0 + wn + ct * 16 + col;
        float bb = bias[gc];
#pragma unroll
        for (int rt = 0; rt < 4; ++rt) {
#pragma unroll
            for (int reg = 0; reg < 4; ++reg) {
                int gr = m0 + wm + rt * 16 + quad * 4 + reg;
                C[(size_t)gr * CBIN_ + gc] = acc[rt][ct][reg] + bb;
            }
        }
    }
}

// ---------------- argmax: 256 rows/block, 8 waves sharing each staged chunk ----------
// Same protected per-wave regime as round-5 (64 VGPR live set, 38.4 KB LDS/block,
// double buffer + __syncthreads per chunk -- DO NOT grow either; see R3/R4/R7/R8
// ledger). Only the sharing factor changes: 8 waves per block instead of 4, so embed
// staging traffic and per-CU barrier-drain events HALVE (512 blocks x 256 KB = 128 MB;
// 2 blocks/CU x 8 waves = 16 waves/CU, same occupancy as before).
__global__ __launch_bounds__(512, 4) void argmax2(const float* __restrict__ h,
                                                  const ushort_t* __restrict__ ehswz,
                                                  const ushort_t* __restrict__ elswz,
                                                  const float* __restrict__ esq,
                                                  const float* __restrict__ embed,
                                                  float* __restrict__ outIdxF,
                                                  int* __restrict__ outIdxI) {
    __shared__ ushort_t EB[2][2][4096];   // [buf][hi/lo][64 codes * 64 elems] = 32 KB
    __shared__ float    ESQ[CBS_];
    __shared__ int BIDX[256];
    __shared__ int FLAG[256];
    __shared__ int NFLAG;

    const int tid  = threadIdx.x;
    const int lane = tid & 63;
    const int w    = tid >> 6;            // 0..7
    const int quad = lane >> 4;
    const int col  = lane & 15;
    const int r0   = blockIdx.x * 256;

    if (tid == 0) NFLAG = 0;
    if (tid < 256) *(float4*)&ESQ[tid * 4] = *(const float4*)(esq + tid * 4);

    // A fragments: wave reads its 32 rows (16 contiguous rows x 256 B per rt)
    short8 AH[2][2], AL[2][2];
#pragma unroll
    for (int rt = 0; rt < 2; ++rt) {
        const float* hp = h + (size_t)(r0 + w * 32 + rt * 16 + col) * 64 + quad * 8;
#pragma unroll
        for (int ks = 0; ks < 2; ++ks) {
            float4 u0 = *(const float4*)(hp + ks * 32);
            float4 u1 = *(const float4*)(hp + ks * 32 + 4);
            float vv[8] = {u0.x, u0.y, u0.z, u0.w, u1.x, u1.y, u1.z, u1.w};
            short8 hh, ll;
#pragma unroll
            for (int j = 0; j < 8; ++j) {
                ushort_t hi = f2bf(vv[j]);
                hh[j] = (short)hi;
                ll[j] = (short)f2bf(vv[j] - bf2f(hi));
            }
            AH[rt][ks] = hh;
            AL[rt][ks] = ll;
        }
    }

    // stage: with 512 threads, ONE cp16 per thread per plane covers the 16-KB chunk
#define STAGE(ch, b)                                                          \
    do {                                                                      \
        int eo = (ch) * 4096 + tid * 8;                                       \
        int wo = w * 512;                                                     \
        async_cp16(&EB[b][0][wo], ehswz + eo);                                \
        async_cp16(&EB[b][1][wo], elswz + eo);                                \
    } while (0)

    STAGE(0, 0);

    float v1[8], v2[8];
    int   i1[8];
#pragma unroll
    for (int s = 0; s < 8; ++s) { v1[s] = -3.4e38f; v2[s] = -3.4e38f; i1[s] = 0; }

    __syncthreads();   // chunk0 staged (vmcnt drained), ESQ + NFLAG visible

    int cur = 0;
    for (int ch = 0; ch < 16; ++ch) {
        if (ch < 15) STAGE(ch + 1, cur ^ 1);
#pragma unroll
        for (int ct = 0; ct < 4; ++ct) {
            const int lc = ct * 16 + col;
            const int x7 = col & 7;
            const int o0 = lc * 64 + (((quad)     ^ x7) << 3);
            const int o1 = lc * 64 + (((quad + 4) ^ x7) << 3);
            short8 BH0 = *(const short8*)&EB[cur][0][o0];
            short8 BH1 = *(const short8*)&EB[cur][0][o1];
            short8 BL0 = *(const short8*)&EB[cur][1][o0];
            short8 BL1 = *(const short8*)&EB[cur][1][o1];
            const int code = ch * 64 + lc;
            float eq = ESQ[code];
#pragma unroll
            for (int rt = 0; rt < 2; ++rt) {
                f32x4 acc = {0.f, 0.f, 0.f, 0.f};
                acc = mfma_bf16(AH[rt][0], BH0, acc);
                acc = mfma_bf16(AH[rt][1], BH1, acc);
                acc = mfma_bf16(AH[rt][0], BL0, acc);
                acc = mfma_bf16(AH[rt][1], BL1, acc);
                acc = mfma_bf16(AL[rt][0], BH0, acc);
                acc = mfma_bf16(AL[rt][1], BH1, acc);
#pragma unroll
                for (int reg = 0; reg < 4; ++reg) {
                    const int st = rt * 4 + reg;
                    float sc = fmaf(2.f, acc[reg], -eq);
                    // runner-up: median(sc, v1, v2) == max(v2, min(sc, v1))
                    v2[st] = __builtin_amdgcn_fmed3f(sc, v1[st], v2[st]);
                    bool gt = sc > v1[st];
                    v1[st] = fmaxf(v1[st], sc);
                    i1[st] = gt ? code : i1[st];
                }
            }
        }
        __syncthreads();   // staging of ch+1 complete; all waves done reading buf cur
        cur ^= 1;
    }
#undef STAGE

#pragma unroll
    for (int st = 0; st < 8; ++st) {
#pragma unroll
        for (int m = 1; m <= 8; m <<= 1) {
            float ov1 = __shfl_xor(v1[st], m);
            int   oi1 = __shfl_xor(i1[st], m);
            float ov2 = __shfl_xor(v2[st], m);
            float losr = fminf(v1[st], ov1);
            v2[st] = fmaxf(fmaxf(v2[st], ov2), losr);
            bool take = (ov1 > v1[st]) || (ov1 == v1[st] && oi1 < i1[st]);
            v1[st] = take ? ov1 : v1[st];
            i1[st] = take ? oi1 : i1[st];
        }
        if (col == 0) {
            int rt = st >> 2, reg = st & 3;
            int row_l = w * 32 + rt * 16 + quad * 4 + reg;
            BIDX[row_l] = i1[st];
            if (v1[st] - v2[st] < MARGIN) {
                int p = atomicAdd(&NFLAG, 1);
                FLAG[p] = row_l;
            }
        }
    }
    __syncthreads();

    int nf = NFLAG;
    for (int i = w; i < nf; i += 8) {
        int row_l = FLAG[i];
        const float* hr = h + (size_t)(r0 + row_l) * 64;
        float accf[16];
#pragma unroll
        for (int j = 0; j < 16; ++j) accf[j] = 0.f;
        for (int d4 = 0; d4 < 16; ++d4) {
            float4 hv = *(const float4*)(hr + d4 * 4);
#pragma unroll
            for (int j = 0; j < 16; ++j) {
                int c = lane + 64 * j;
                float4 ev = *(const float4*)(embed + (size_t)c * 64 + d4 * 4);
                accf[j] += hv.x * ev.x + hv.y * ev.y + hv.z * ev.z + hv.w * ev.w;
            }
        }
        float best = -3.4e38f; int bi = 0;
#pragma unroll
        for (int j = 0; j < 16; ++j) {
            int c = lane + 64 * j;
            float sc = 2.f * accf[j] - ESQ[c];
            if (sc > best) { best = sc; bi = c; }
        }
#pragma unroll
        for (int m = 1; m <= 32; m <<= 1) {
            float ob = __shfl_xor(best, m);
            int  obi = __shfl_xor(bi, m);
            if (ob > best || (ob == best && obi < bi)) { best = ob; bi = obi; }
        }
        if (lane == 0) BIDX[row_l] = bi;
    }
    __syncthreads();

    if (tid < 256) {
        int b = BIDX[tid];
        outIdxF[r0 + tid] = (float)b;
        outIdxI[r0 + tid] = b;
    }
}

// ---------------- GEMM3: out = gather(embed_bf16, idx) @ W_out + b_out ----------------
// Round-8/9 version: async double-buffered staging via global_load_lds into TRANSPOSED
// [slot(8)][row(128)] LDS; row is the fast axis -> conflict-free with a LINEAR dest.
// Q's per-lane global source un-XORs the swizzled ehswz row. STAGE(head+1) flies under
// head's 32 MFMA; one __syncthreads per head drains it.
__global__ __launch_bounds__(256) void gemm_out_bf16(const ushort_t* __restrict__ ehswz,
                                                     const int* __restrict__ idx,
                                                     const ushort_t* __restrict__ WbfT,
                                                     const float* __restrict__ bias,
                                                     float* __restrict__ C) {
    __shared__ ushort_t Qs[2][8192];   // [buf][slot*128+row][8] = 16 KB per buf
    __shared__ ushort_t Ws[2][8192];
    __shared__ int idxs[128 * HEADS_]; // 4 KB

    const int tid  = threadIdx.x;
    const int lane = tid & 63;
    const int w    = tid >> 6;
    const int quad = lane >> 4;
    const int col  = lane & 15;
    const int m0   = blockIdx.y * 128;
    const int n0   = blockIdx.x * 128;
    const int wm   = (w & 1) * 64;
    const int wn   = (w >> 1) * 64;

#pragma unroll
    for (int s = 0; s < 4; ++s) {
        int f = s * 256 + tid;
        idxs[f] = idx[(size_t)m0 * HEADS_ + f];
    }
    __syncthreads();   // idxs visible to all waves before STAGE reads them

#define STAGEO(hd, b)                                                         \
    do {                                                                      \
        _Pragma("unroll")                                                     \
        for (int j2 = 0; j2 < 2; ++j2) {                                      \
            const int j = w * 2 + j2;                                         \
            _Pragma("unroll")                                                 \
            for (int r2 = 0; r2 < 2; ++r2) {                                  \
                const int row = r2 * 64 + lane;                               \
                const int e   = idxs[row * HEADS_ + (hd)];                    \
                async_cp16(&Qs[b][(j * 128 + r2 * 64) * 8],                   \
                           ehswz + (size_t)e * 64 + ((j ^ (e & 7)) << 3));    \
                async_cp16(&Ws[b][(j * 128 + r2 * 64) * 8],                   \
                           WbfT + (size_t)(n0 + row) * CBIN_ + (hd)*64 + j*8);\
            }                                                                 \
        }                                                                     \
    } while (0)

    f32x4 acc[4][4];
#pragma unroll
    for (int rt = 0; rt < 4; ++rt)
#pragma unroll
        for (int ct = 0; ct < 4; ++ct) acc[rt][ct] = (f32x4){0.f, 0.f, 0.f, 0.f};

    STAGEO(0, 0);
    __syncthreads();   // head-0 tiles staged (vmcnt drained)

    int b = 0;
#pragma unroll 1
    for (int hd = 0; hd < HEADS_; ++hd) {
        if (hd < 7) STAGEO(hd + 1, b ^ 1);
#pragma unroll
        for (int ks = 0; ks < 2; ++ks) {
            const int sbase = ((ks * 4 + quad) * 128) * 8;
            short8 a[4], bb[4];
#pragma unroll
            for (int rt = 0; rt < 4; ++rt)
                a[rt] = *(const short8*)&Qs[b][sbase + (wm + rt * 16 + col) * 8];
#pragma unroll
            for (int ct = 0; ct < 4; ++ct)
                bb[ct] = *(const short8*)&Ws[b][sbase + (wn + ct * 16 + col) * 8];
#pragma unroll
            for (int rt = 0; rt < 4; ++rt)
#pragma unroll
                for (int ct = 0; ct < 4; ++ct)
                    acc[rt][ct] = mfma_bf16(a[rt], bb[ct], acc[rt][ct]);
        }
        __syncthreads();   // STAGE(hd+1) landed; readers of buf b done before overwrite
        b ^= 1;
    }
#undef STAGEO

#pragma unroll
    for (int ct = 0; ct < 4; ++ct) {
        int gc = n0 + wn + ct * 16 + col;
        float bbias = bias[gc];
#pragma unroll
        for (int rt = 0; rt < 4; ++rt) {
#pragma unroll
            for (int reg = 0; reg < 4; ++reg) {
                int gr = m0 + wm + rt * 16 + quad * 4 + reg;
                C[(size_t)gr * DIM_ + gc] = acc[rt][ct][reg] + bbias;
            }
        }
    }
}

extern "C" void kernel_launch(void* const* d_in, const int* in_sizes, int n_in,
                              void* d_out, int out_size, void* d_ws, size_t ws_size,
                              hipStream_t stream) {
    const float* x     = (const float*)d_in[0];
    const float* W_in  = (const float*)d_in[1];
    const float* b_in  = (const float*)d_in[2];
    const float* W_out = (const float*)d_in[3];
    const float* b_out = (const float*)d_in[4];
    const float* embed = (const float*)d_in[5];

    float* out     = (float*)d_out;
    float* outIdxF = out + (size_t)M_ * DIM_;

    // workspace layout (38.5 MB total)
    char* ws = (char*)d_ws;
    float*    h     = (float*)ws;                                   // 33,554,432 B
    int*      idxI  = (int*)(ws + 33554432);                        //    524,288 B
    float*    esq   = (float*)(ws + 34078720);                      //      4,096 B
    ushort_t* ehswz = (ushort_t*)(ws + 34082816);                   //    131,072 B (swizzled hi)
    ushort_t* elswz = (ushort_t*)(ws + 34213888);                   //    131,072 B (swizzled lo)
    ushort_t* WbfT  = (ushort_t*)(ws + 34344960);                   //  1,048,576 B
    ushort_t* W1T   = (ushort_t*)(ws + 35393536);                   //  1,048,576 B
    ushort_t* W2T   = (ushort_t*)(ws + 36442112);                   //  1,048,576 B
    ushort_t* W3T   = (ushort_t*)(ws + 37490688);                   //  1,048,576 B

    prep_embed<<<dim3(CBS_ * CBD_ / 256), dim3(256), 0, stream>>>(embed, ehswz, elswz, esq);
    transposeW<<<dim3(DIM_ / 64, CBIN_ / 64), dim3(256), 0, stream>>>(W_out, WbfT);
    split_WinT<<<dim3(CBIN_ / 64, DIM_ / 64), dim3(256), 0, stream>>>(W_in, W1T, W2T, W3T);
    gemm_in_x6<<<dim3(CBIN_ / 128, M_ / 128), dim3(512), 0, stream>>>(x, W1T, W2T, W3T,
                                                                      b_in, h);
    argmax2<<<dim3(M2_ / 256), dim3(512), 0, stream>>>(h, ehswz, elswz, esq, embed,
                                                       outIdxF, idxI);
    gemm_out_bf16<<<dim3(DIM_ / 128, M_ / 128), dim3(256), 0, stream>>>(ehswz, idxI, WbfT,
                                                                        b_out, out);
}